// Round 5
// baseline (1014.912 us; speedup 1.0000x reference)
//
#include <hip/hip_runtime.h>
#include <math.h>

#define NCLS 16
#define DIM  64
#define GBLK 48   // gram blocks per class: 16*48 = 768 = 256 CUs * 3 blocks/CU

// ---------------- K1a: init counters + Gram buffer ----------------
__global__ void k_init(int* __restrict__ cnt, float* __restrict__ G) {
    int t = blockIdx.x * blockDim.x + threadIdx.x;
    if (t < NCLS) cnt[t] = 0;
    for (int i = t; i < NCLS * DIM * DIM; i += gridDim.x * blockDim.x) G[i] = 0.f;
}

// ---------------- K1b: class histogram (16x sub-banked LDS) ----------------
__global__ void k_hist(const int* __restrict__ label, int n, int* __restrict__ cnt) {
    __shared__ int h[NCLS * 16];
    for (int i = threadIdx.x; i < NCLS * 16; i += 256) h[i] = 0;
    __syncthreads();
    const int sub = threadIdx.x & 15;
    int stride = gridDim.x * blockDim.x;
    for (int i = blockIdx.x * blockDim.x + threadIdx.x; i < n; i += stride)
        atomicAdd(&h[label[i] * 16 + sub], 1);
    __syncthreads();
    if (threadIdx.x < NCLS) {
        int s = 0;
#pragma unroll
        for (int j = 0; j < 16; j++) s += h[threadIdx.x * 16 + j];
        atomicAdd(&cnt[threadIdx.x], s);
    }
}

// ---------------- K1c: tiny exclusive scan ----------------
__global__ void k_scan(const int* __restrict__ cnt, int* __restrict__ base,
                       int* __restrict__ cursor) {
    if (threadIdx.x == 0) {
        int s = 0;
        for (int c = 0; c < NCLS; c++) { base[c] = s; cursor[c] = s; s += cnt[c]; }
    }
}

// ---------------- K1d: scatter row indices into class buckets ----------------
// R3 version. NOTE: reservation must stay at 16 atomics/block to 16 DISTINCT
// words. R4's sub-banked variant did 65536 device atomics into one cache line
// -> 577 us of cross-XCD line ping-pong.
__global__ void k_scatter(const int* __restrict__ label, int n,
                          int* __restrict__ cursor, int* __restrict__ idx) {
    __shared__ int h[NCLS];
    __shared__ int cur[NCLS];
    if (threadIdx.x < NCLS) h[threadIdx.x] = 0;
    __syncthreads();
    int stride = gridDim.x * blockDim.x;
    for (int i = blockIdx.x * blockDim.x + threadIdx.x; i < n; i += stride)
        atomicAdd(&h[label[i]], 1);
    __syncthreads();
    if (threadIdx.x < NCLS)
        cur[threadIdx.x] = atomicAdd(&cursor[threadIdx.x], h[threadIdx.x]);
    __syncthreads();
    for (int i = blockIdx.x * blockDim.x + threadIdx.x; i < n; i += stride) {
        int p = atomicAdd(&cur[label[i]], 1);
        idx[p] = i;
    }
}

// ---------------- K2: per-class Gram, software-pipelined ----------------
// grid = 16 classes * GBLK blocks (exactly 3 resident blocks/CU at
// __launch_bounds__(256,3)), block = 256 (4 waves). Each wave owns the full
// 64x64 outer product (8x8/lane). K-loop is manually 2x-unrolled with
// ping-pong register buffers: next group's row loads + next-next indices are
// issued BEFORE the fma burst, so ~600-900 cyc gather latency overlaps 256 cyc
// of fma x 3 waves/SIMD. VGPR ~ 64 acc + 2x32 bufs + addr ~ 145 < 168 cap.
__global__ __launch_bounds__(256, 3) void k_gram(const float* __restrict__ feat,
                                                 const int* __restrict__ idx,
                                                 const int* __restrict__ base,
                                                 const int* __restrict__ cnt,
                                                 float* __restrict__ G) {
    const int c    = blockIdx.x & (NCLS - 1);
    const int blk  = blockIdx.x >> 4;          // 0..GBLK-1
    const int wave = threadIdx.x >> 6;
    const int lane = threadIdx.x & 63;
    const int gw   = blk * 4 + wave;           // 0..4*GBLK-1
    const int r0   = (lane >> 3) << 3;
    const int c0   = (lane & 7) << 3;
    const int m    = cnt[c];
    const int b0   = base[c];
    const int STEP = 4 * GBLK * 2;             // waves-per-class * q(=2)

    float acc[8][8];
#pragma unroll
    for (int j = 0; j < 8; j++)
#pragma unroll
        for (int k = 0; k < 8; k++) acc[j][k] = 0.f;

    auto load_idx = [&](int p, int (&J)[2]) {
#pragma unroll
        for (int q = 0; q < 2; q++) J[q] = (p + q < m) ? idx[b0 + p + q] : -1;
    };
    auto load_group = [&](const int (&J)[2], float4 (&A)[2][2], float4 (&B)[2][2]) {
#pragma unroll
        for (int q = 0; q < 2; q++) {
            if (J[q] >= 0) {                   // wave-uniform branch
                const float* rp = feat + (size_t)J[q] * DIM;
                A[q][0] = *(const float4*)(rp + r0);
                A[q][1] = *(const float4*)(rp + r0 + 4);
                B[q][0] = *(const float4*)(rp + c0);
                B[q][1] = *(const float4*)(rp + c0 + 4);
            } else {
                float4 z = make_float4(0.f, 0.f, 0.f, 0.f);
                A[q][0] = z; A[q][1] = z; B[q][0] = z; B[q][1] = z;
            }
        }
    };
    auto fma_group = [&](const float4 (&A)[2][2], const float4 (&B)[2][2]) {
#pragma unroll
        for (int q = 0; q < 2; q++) {
            float av[8] = {A[q][0].x, A[q][0].y, A[q][0].z, A[q][0].w,
                           A[q][1].x, A[q][1].y, A[q][1].z, A[q][1].w};
            float bv[8] = {B[q][0].x, B[q][0].y, B[q][0].z, B[q][0].w,
                           B[q][1].x, B[q][1].y, B[q][1].z, B[q][1].w};
#pragma unroll
            for (int j = 0; j < 8; j++)
#pragma unroll
                for (int k = 0; k < 8; k++)
                    acc[j][k] = fmaf(av[j], bv[k], acc[j][k]);
        }
    };

    const int p0 = gw * 2;
    int j1[2], j2[2];
    float4 Aa[2][2], Ab[2][2], Ba[2][2], Bb[2][2];
    load_idx(p0, j1);
    load_group(j1, Aa, Ab);            // rows for p0
    load_idx(p0 + STEP, j2);           // indices for p0+STEP

    for (int p = p0; p < m; p += 2 * STEP) {
        load_group(j2, Ba, Bb);        // issue rows for p+STEP
        load_idx(p + 2 * STEP, j1);    // prefetch indices for p+2*STEP
        fma_group(Aa, Ab);             // compute rows p (hides Ba/Bb latency)
        load_group(j1, Aa, Ab);        // issue rows for p+2*STEP
        load_idx(p + 3 * STEP, j2);    // prefetch indices for p+3*STEP
        fma_group(Ba, Bb);             // compute rows p+STEP
    }

    // ---- phased LDS block reduction (race-free), then coalesced atomics ----
    __shared__ float tile[DIM * DIM];
    for (int w = 0; w < 4; w++) {
        if (wave == w) {
            float* t = tile + r0 * DIM + c0;
            if (w == 0) {
#pragma unroll
                for (int j = 0; j < 8; j++) {
                    *(float4*)(t + j * DIM)     = make_float4(acc[j][0], acc[j][1], acc[j][2], acc[j][3]);
                    *(float4*)(t + j * DIM + 4) = make_float4(acc[j][4], acc[j][5], acc[j][6], acc[j][7]);
                }
            } else {
#pragma unroll
                for (int j = 0; j < 8; j++) {
                    float4 u0 = *(float4*)(t + j * DIM);
                    float4 u1 = *(float4*)(t + j * DIM + 4);
                    u0.x += acc[j][0]; u0.y += acc[j][1]; u0.z += acc[j][2]; u0.w += acc[j][3];
                    u1.x += acc[j][4]; u1.y += acc[j][5]; u1.z += acc[j][6]; u1.w += acc[j][7];
                    *(float4*)(t + j * DIM)     = u0;
                    *(float4*)(t + j * DIM + 4) = u1;
                }
            }
        }
        __syncthreads();
    }
    float* g = G + c * DIM * DIM;
    for (int e = threadIdx.x; e < DIM * DIM; e += 256)
        atomicAdd(&g[e], tile[e]);
}

// ---------------- K3: top eigenvector per class (4-wave cooperative) ----
// (unchanged from R4 — validated: trace-moment shift, 7 LDS squarings to
// C=(G-sigma I)^128, column-of-max-diag start, 8 applies, ~20 us for 16 blocks)
__global__ __launch_bounds__(256, 1) void k_eig(const float* __restrict__ G,
                                                float* __restrict__ V) {
    const int c    = blockIdx.x;
    const int t    = threadIdx.x;
    const int wave = t >> 6;
    const int lane = t & 63;
    __shared__ float shA[DIM * DIM];
    __shared__ float shB[DIM * DIM];
    __shared__ float shP[4 * DIM];
    __shared__ float shRed[4];
    __shared__ float shV[DIM];

    {
        const float4* g4 = (const float4*)(G + c * DIM * DIM);
        float4* a4 = (float4*)shA;
#pragma unroll
        for (int j = 0; j < 4; j++) a4[t + 256 * j] = g4[t + 256 * j];
    }
    __syncthreads();

    float ss = 0.f;
    {
        const float4* a4 = (const float4*)shA;
#pragma unroll
        for (int j = 0; j < 4; j++) {
            float4 x = a4[t + 256 * j];
            ss = fmaf(x.x, x.x, fmaf(x.y, x.y, fmaf(x.z, x.z, fmaf(x.w, x.w, ss))));
        }
    }
#pragma unroll
    for (int m = 1; m < 64; m <<= 1) ss += __shfl_xor(ss, m);
    if (lane == 0) shRed[wave] = ss;
    __syncthreads();
    if (wave == 0) {
        float s2 = shRed[0] + shRed[1] + shRed[2] + shRed[3];
        float d  = shA[lane * 65];
        float sd = d;
#pragma unroll
        for (int m = 1; m < 64; m <<= 1) sd += __shfl_xor(sd, m);
        float mu    = sd * (1.f / 64.f);
        float var   = fmaxf(s2 * (1.f / 64.f) - mu * mu, 0.f);
        float sigma = mu - 0.2f * sqrtf(var);
        shA[lane * 65] = d - sigma;
    }
    __syncthreads();

    float* cur = shA;
    float* nxt = shB;
    const int ra = wave * 16 + ((lane >> 3) << 1);
    const int c0 = (lane & 7) << 3;
    for (int sq = 0; sq < 7; sq++) {
        float acc[2][8];
#pragma unroll
        for (int j = 0; j < 8; j++) { acc[0][j] = 0.f; acc[1][j] = 0.f; }
#pragma unroll 4
        for (int k = 0; k < DIM; k++) {
            const float* rk = cur + k * DIM;
            float2 a2 = *(const float2*)(rk + ra);
            float4 b0 = *(const float4*)(rk + c0);
            float4 b1 = *(const float4*)(rk + c0 + 4);
            acc[0][0] = fmaf(a2.x, b0.x, acc[0][0]);
            acc[0][1] = fmaf(a2.x, b0.y, acc[0][1]);
            acc[0][2] = fmaf(a2.x, b0.z, acc[0][2]);
            acc[0][3] = fmaf(a2.x, b0.w, acc[0][3]);
            acc[0][4] = fmaf(a2.x, b1.x, acc[0][4]);
            acc[0][5] = fmaf(a2.x, b1.y, acc[0][5]);
            acc[0][6] = fmaf(a2.x, b1.z, acc[0][6]);
            acc[0][7] = fmaf(a2.x, b1.w, acc[0][7]);
            acc[1][0] = fmaf(a2.y, b0.x, acc[1][0]);
            acc[1][1] = fmaf(a2.y, b0.y, acc[1][1]);
            acc[1][2] = fmaf(a2.y, b0.z, acc[1][2]);
            acc[1][3] = fmaf(a2.y, b0.w, acc[1][3]);
            acc[1][4] = fmaf(a2.y, b1.x, acc[1][4]);
            acc[1][5] = fmaf(a2.y, b1.y, acc[1][5]);
            acc[1][6] = fmaf(a2.y, b1.z, acc[1][6]);
            acc[1][7] = fmaf(a2.y, b1.w, acc[1][7]);
        }
        *(float4*)(nxt + (ra + 0) * DIM + c0)     = make_float4(acc[0][0], acc[0][1], acc[0][2], acc[0][3]);
        *(float4*)(nxt + (ra + 0) * DIM + c0 + 4) = make_float4(acc[0][4], acc[0][5], acc[0][6], acc[0][7]);
        *(float4*)(nxt + (ra + 1) * DIM + c0)     = make_float4(acc[1][0], acc[1][1], acc[1][2], acc[1][3]);
        *(float4*)(nxt + (ra + 1) * DIM + c0 + 4) = make_float4(acc[1][4], acc[1][5], acc[1][6], acc[1][7]);
        __syncthreads();
        float4 xs[4];
        float mx = 0.f;
        {
            const float4* n4 = (const float4*)nxt;
#pragma unroll
            for (int j = 0; j < 4; j++) {
                float4 x = n4[t + 256 * j];
                xs[j] = x;
                mx = fmaxf(mx, fmaxf(fmaxf(fabsf(x.x), fabsf(x.y)),
                                     fmaxf(fabsf(x.z), fabsf(x.w))));
            }
        }
#pragma unroll
        for (int m = 1; m < 64; m <<= 1) mx = fmaxf(mx, __shfl_xor(mx, m));
        if (lane == 0) shRed[wave] = mx;
        __syncthreads();
        float gm = fmaxf(fmaxf(shRed[0], shRed[1]), fmaxf(shRed[2], shRed[3]));
        float inv = (gm > 0.f) ? (1.0f / gm) : 1.0f;
        {
            float4* n4 = (float4*)nxt;
#pragma unroll
            for (int j = 0; j < 4; j++) {
                float4 x = xs[j];
                n4[t + 256 * j] = make_float4(x.x * inv, x.y * inv, x.z * inv, x.w * inv);
            }
        }
        __syncthreads();
        float* tmp = cur; cur = nxt; nxt = tmp;
    }

    if (wave == 0) {
        float d = cur[lane * 65];
        float dmax = d;
#pragma unroll
        for (int m = 1; m < 64; m <<= 1) dmax = fmaxf(dmax, __shfl_xor(dmax, m));
        unsigned long long bal = __ballot(d == dmax);
        int jstar = __ffsll((long long)bal) - 1;
        shV[lane] = cur[jstar * DIM + lane];
    }
    __syncthreads();

    for (int it = 0; it < 8; it++) {
        float part = 0.f;
#pragma unroll
        for (int j = 0; j < 16; j++) {
            int k = wave * 16 + j;
            part = fmaf(cur[k * DIM + lane], shV[k], part);
        }
        shP[wave * DIM + lane] = part;
        __syncthreads();
        if (wave == 0)
            shV[lane] = shP[lane] + shP[64 + lane] + shP[128 + lane] + shP[192 + lane];
        __syncthreads();
    }

    if (wave == 0) {
        float val = shV[lane];
        float nn = val * val;
#pragma unroll
        for (int m = 1; m < 64; m <<= 1) nn += __shfl_xor(nn, m);
        float inv = (nn > 1e-30f) ? rsqrtf(nn) : 1.0f;
        float am = fabsf(val);
        float bm = am;
#pragma unroll
        for (int m = 1; m < 64; m <<= 1) bm = fmaxf(bm, __shfl_xor(bm, m));
        unsigned long long bal = __ballot(am == bm);
        int jm = __ffsll((long long)bal) - 1;
        float vm = __shfl(val, jm);
        float s = (vm < 0.f) ? -inv : inv;
        V[c * DIM + lane] = val * s;
    }
}

// ---------------- K4: given[i] = <feat_i, V[label_i]> ----------------
__global__ __launch_bounds__(256) void k_out(const float* __restrict__ feat,
                                             const int* __restrict__ label,
                                             const float* __restrict__ V,
                                             float* __restrict__ out, int n) {
    int i = blockIdx.x * blockDim.x + threadIdx.x;
    if (i >= n) return;
    const float4* rp = (const float4*)(feat + (size_t)i * DIM);
    const float4* vp = (const float4*)(V + label[i] * DIM);
    float s0 = 0, s1 = 0, s2 = 0, s3 = 0;
#pragma unroll
    for (int j = 0; j < 16; j++) {
        float4 a = rp[j], b = vp[j];
        s0 = fmaf(a.x, b.x, s0);
        s1 = fmaf(a.y, b.y, s1);
        s2 = fmaf(a.z, b.z, s2);
        s3 = fmaf(a.w, b.w, s3);
    }
    out[i] = (s0 + s1) + (s2 + s3);
}

extern "C" void kernel_launch(void* const* d_in, const int* in_sizes, int n_in,
                              void* d_out, int out_size, void* d_ws, size_t ws_size,
                              hipStream_t stream) {
    const float* feat  = (const float*)d_in[0];
    const int*   label = (const int*)d_in[1];
    const int    n     = in_sizes[1];
    float*       out   = (float*)d_out;

    int*   cnt    = (int*)d_ws;
    int*   base   = cnt + 16;
    int*   cursor = cnt + 32;
    float* G      = (float*)(cnt + 64);          // 16 * 4096 floats
    float* V      = G + NCLS * DIM * DIM;        // 16 * 64 floats
    int*   idx    = (int*)(V + NCLS * DIM);      // n ints

    k_init<<<64, 256, 0, stream>>>(cnt, G);
    k_hist<<<256, 256, 0, stream>>>(label, n, cnt);
    k_scan<<<1, 64, 0, stream>>>(cnt, base, cursor);
    k_scatter<<<256, 256, 0, stream>>>(label, n, cursor, idx);
    k_gram<<<NCLS * GBLK, 256, 0, stream>>>(feat, idx, base, cnt, G);
    k_eig<<<NCLS, 256, 0, stream>>>(G, V);
    k_out<<<(n + 255) / 256, 256, 0, stream>>>(feat, label, V, out, n);
}

// Round 6
// 519.683 us; speedup vs baseline: 1.9529x; 1.9529x over previous
//
#include <hip/hip_runtime.h>
#include <math.h>

#define NCLS 16
#define DIM  64
#define GBLK 48   // gram blocks per class: 16*48 = 768 = 256 CUs * 3 blocks/CU

// ---------------- K1a: init counters + Gram buffer ----------------
__global__ void k_init(int* __restrict__ cnt, float* __restrict__ G) {
    int t = blockIdx.x * blockDim.x + threadIdx.x;
    if (t < NCLS) cnt[t] = 0;
    for (int i = t; i < NCLS * DIM * DIM; i += gridDim.x * blockDim.x) G[i] = 0.f;
}

// ---------------- K1b: class histogram (16x sub-banked LDS) ----------------
__global__ void k_hist(const int* __restrict__ label, int n, int* __restrict__ cnt) {
    __shared__ int h[NCLS * 16];
    for (int i = threadIdx.x; i < NCLS * 16; i += 256) h[i] = 0;
    __syncthreads();
    const int sub = threadIdx.x & 15;
    int stride = gridDim.x * blockDim.x;
    for (int i = blockIdx.x * blockDim.x + threadIdx.x; i < n; i += stride)
        atomicAdd(&h[label[i] * 16 + sub], 1);
    __syncthreads();
    if (threadIdx.x < NCLS) {
        int s = 0;
#pragma unroll
        for (int j = 0; j < 16; j++) s += h[threadIdx.x * 16 + j];
        atomicAdd(&cnt[threadIdx.x], s);
    }
}

// ---------------- K1c: tiny exclusive scan ----------------
__global__ void k_scan(const int* __restrict__ cnt, int* __restrict__ base,
                       int* __restrict__ cursor) {
    if (threadIdx.x == 0) {
        int s = 0;
        for (int c = 0; c < NCLS; c++) { base[c] = s; cursor[c] = s; s += cnt[c]; }
    }
}

// ---------------- K1d: scatter row indices into class buckets ----------------
// R3 version. Reservation = 16 atomics/block to 16 DISTINCT words (R4's
// 65536-atomics-into-one-line variant cost 577 us of cross-XCD ping-pong).
__global__ void k_scatter(const int* __restrict__ label, int n,
                          int* __restrict__ cursor, int* __restrict__ idx) {
    __shared__ int h[NCLS];
    __shared__ int cur[NCLS];
    if (threadIdx.x < NCLS) h[threadIdx.x] = 0;
    __syncthreads();
    int stride = gridDim.x * blockDim.x;
    for (int i = blockIdx.x * blockDim.x + threadIdx.x; i < n; i += stride)
        atomicAdd(&h[label[i]], 1);
    __syncthreads();
    if (threadIdx.x < NCLS)
        cur[threadIdx.x] = atomicAdd(&cursor[threadIdx.x], h[threadIdx.x]);
    __syncthreads();
    for (int i = blockIdx.x * blockDim.x + threadIdx.x; i < n; i += stride) {
        int p = atomicAdd(&cur[label[i]], 1);
        idx[p] = i;
    }
}

// ---------------- K2: per-class Gram via register 8x8 tiles ----------------
// R2/R3 code shape (straight-line, arrays indexed ONLY by fully-unrolled
// compile-time indices -> provably stays in VGPRs; R5's lambda-by-reference
// buffers were demoted to scratch: VGPR 84 + 2.3 GB spill traffic).
// q=4 rows/iter: 256 independent fmas per iter, loads issued at loop top,
// next indices prefetched before the fma burst. __launch_bounds__(256,3)
// -> 170-VGPR cap (demand ~145), GBLK=48 -> exactly 3 blocks/CU so each
// SIMD interleaves 3 waves of 512-cyc fma bursts against ~900-cyc HBM lat.
__global__ __launch_bounds__(256, 3) void k_gram(const float* __restrict__ feat,
                                                 const int* __restrict__ idx,
                                                 const int* __restrict__ base,
                                                 const int* __restrict__ cnt,
                                                 float* __restrict__ G) {
    const int c    = blockIdx.x & (NCLS - 1);
    const int blk  = blockIdx.x >> 4;          // 0..GBLK-1
    const int wave = threadIdx.x >> 6;
    const int lane = threadIdx.x & 63;
    const int gw   = blk * 4 + wave;           // 0..4*GBLK-1
    const int r0   = (lane >> 3) << 3;
    const int c0   = (lane & 7) << 3;
    const int m    = cnt[c];
    const int b0   = base[c];
    const int STEP = 4 * GBLK * 4;             // waves-per-class * q(=4)

    float acc[8][8];
#pragma unroll
    for (int j = 0; j < 8; j++)
#pragma unroll
        for (int k = 0; k < 8; k++) acc[j][k] = 0.f;

    int ii[4];
    const int p0 = gw * 4;
#pragma unroll
    for (int q = 0; q < 4; q++) ii[q] = (p0 + q < m) ? idx[b0 + p0 + q] : -1;

    for (int p = p0; p < m; p += STEP) {
        float4 xa[4][2], xb[4][2];
#pragma unroll
        for (int q = 0; q < 4; q++) {
            if (ii[q] >= 0) {                  // wave-uniform branch
                const float* rp = feat + (size_t)ii[q] * DIM;
                xa[q][0] = *(const float4*)(rp + r0);
                xa[q][1] = *(const float4*)(rp + r0 + 4);
                xb[q][0] = *(const float4*)(rp + c0);
                xb[q][1] = *(const float4*)(rp + c0 + 4);
            } else {
                float4 z = make_float4(0.f, 0.f, 0.f, 0.f);
                xa[q][0] = z; xa[q][1] = z; xb[q][0] = z; xb[q][1] = z;
            }
        }
        // prefetch next iteration's indices (hidden under the fma burst)
        const int pn = p + STEP;
#pragma unroll
        for (int q = 0; q < 4; q++) ii[q] = (pn + q < m) ? idx[b0 + pn + q] : -1;

#pragma unroll
        for (int q = 0; q < 4; q++) {
            float av[8] = {xa[q][0].x, xa[q][0].y, xa[q][0].z, xa[q][0].w,
                           xa[q][1].x, xa[q][1].y, xa[q][1].z, xa[q][1].w};
            float bv[8] = {xb[q][0].x, xb[q][0].y, xb[q][0].z, xb[q][0].w,
                           xb[q][1].x, xb[q][1].y, xb[q][1].z, xb[q][1].w};
#pragma unroll
            for (int j = 0; j < 8; j++)
#pragma unroll
                for (int k = 0; k < 8; k++)
                    acc[j][k] = fmaf(av[j], bv[k], acc[j][k]);
        }
    }

    // ---- phased LDS block reduction (race-free), then coalesced atomics ----
    __shared__ float tile[DIM * DIM];
    for (int w = 0; w < 4; w++) {
        if (wave == w) {
            float* t = tile + r0 * DIM + c0;
            if (w == 0) {
#pragma unroll
                for (int j = 0; j < 8; j++) {
                    *(float4*)(t + j * DIM)     = make_float4(acc[j][0], acc[j][1], acc[j][2], acc[j][3]);
                    *(float4*)(t + j * DIM + 4) = make_float4(acc[j][4], acc[j][5], acc[j][6], acc[j][7]);
                }
            } else {
#pragma unroll
                for (int j = 0; j < 8; j++) {
                    float4 u0 = *(float4*)(t + j * DIM);
                    float4 u1 = *(float4*)(t + j * DIM + 4);
                    u0.x += acc[j][0]; u0.y += acc[j][1]; u0.z += acc[j][2]; u0.w += acc[j][3];
                    u1.x += acc[j][4]; u1.y += acc[j][5]; u1.z += acc[j][6]; u1.w += acc[j][7];
                    *(float4*)(t + j * DIM)     = u0;
                    *(float4*)(t + j * DIM + 4) = u1;
                }
            }
        }
        __syncthreads();
    }
    float* g = G + c * DIM * DIM;
    for (int e = threadIdx.x; e < DIM * DIM; e += 256)
        atomicAdd(&g[e], tile[e]);
}

// ---------------- K3: top eigenvector per class (4-wave cooperative) ----
// (unchanged — validated: trace-moment shift, 7 LDS squarings to
// C=(G-sigma I)^128, column-of-max-diag start, 8 applies)
__global__ __launch_bounds__(256, 1) void k_eig(const float* __restrict__ G,
                                                float* __restrict__ V) {
    const int c    = blockIdx.x;
    const int t    = threadIdx.x;
    const int wave = t >> 6;
    const int lane = t & 63;
    __shared__ float shA[DIM * DIM];
    __shared__ float shB[DIM * DIM];
    __shared__ float shP[4 * DIM];
    __shared__ float shRed[4];
    __shared__ float shV[DIM];

    {
        const float4* g4 = (const float4*)(G + c * DIM * DIM);
        float4* a4 = (float4*)shA;
#pragma unroll
        for (int j = 0; j < 4; j++) a4[t + 256 * j] = g4[t + 256 * j];
    }
    __syncthreads();

    float ss = 0.f;
    {
        const float4* a4 = (const float4*)shA;
#pragma unroll
        for (int j = 0; j < 4; j++) {
            float4 x = a4[t + 256 * j];
            ss = fmaf(x.x, x.x, fmaf(x.y, x.y, fmaf(x.z, x.z, fmaf(x.w, x.w, ss))));
        }
    }
#pragma unroll
    for (int m = 1; m < 64; m <<= 1) ss += __shfl_xor(ss, m);
    if (lane == 0) shRed[wave] = ss;
    __syncthreads();
    if (wave == 0) {
        float s2 = shRed[0] + shRed[1] + shRed[2] + shRed[3];
        float d  = shA[lane * 65];
        float sd = d;
#pragma unroll
        for (int m = 1; m < 64; m <<= 1) sd += __shfl_xor(sd, m);
        float mu    = sd * (1.f / 64.f);
        float var   = fmaxf(s2 * (1.f / 64.f) - mu * mu, 0.f);
        float sigma = mu - 0.2f * sqrtf(var);
        shA[lane * 65] = d - sigma;
    }
    __syncthreads();

    float* cur = shA;
    float* nxt = shB;
    const int ra = wave * 16 + ((lane >> 3) << 1);
    const int c0 = (lane & 7) << 3;
    for (int sq = 0; sq < 7; sq++) {
        float acc[2][8];
#pragma unroll
        for (int j = 0; j < 8; j++) { acc[0][j] = 0.f; acc[1][j] = 0.f; }
#pragma unroll 4
        for (int k = 0; k < DIM; k++) {
            const float* rk = cur + k * DIM;
            float2 a2 = *(const float2*)(rk + ra);
            float4 b0 = *(const float4*)(rk + c0);
            float4 b1 = *(const float4*)(rk + c0 + 4);
            acc[0][0] = fmaf(a2.x, b0.x, acc[0][0]);
            acc[0][1] = fmaf(a2.x, b0.y, acc[0][1]);
            acc[0][2] = fmaf(a2.x, b0.z, acc[0][2]);
            acc[0][3] = fmaf(a2.x, b0.w, acc[0][3]);
            acc[0][4] = fmaf(a2.x, b1.x, acc[0][4]);
            acc[0][5] = fmaf(a2.x, b1.y, acc[0][5]);
            acc[0][6] = fmaf(a2.x, b1.z, acc[0][6]);
            acc[0][7] = fmaf(a2.x, b1.w, acc[0][7]);
            acc[1][0] = fmaf(a2.y, b0.x, acc[1][0]);
            acc[1][1] = fmaf(a2.y, b0.y, acc[1][1]);
            acc[1][2] = fmaf(a2.y, b0.z, acc[1][2]);
            acc[1][3] = fmaf(a2.y, b0.w, acc[1][3]);
            acc[1][4] = fmaf(a2.y, b1.x, acc[1][4]);
            acc[1][5] = fmaf(a2.y, b1.y, acc[1][5]);
            acc[1][6] = fmaf(a2.y, b1.z, acc[1][6]);
            acc[1][7] = fmaf(a2.y, b1.w, acc[1][7]);
        }
        *(float4*)(nxt + (ra + 0) * DIM + c0)     = make_float4(acc[0][0], acc[0][1], acc[0][2], acc[0][3]);
        *(float4*)(nxt + (ra + 0) * DIM + c0 + 4) = make_float4(acc[0][4], acc[0][5], acc[0][6], acc[0][7]);
        *(float4*)(nxt + (ra + 1) * DIM + c0)     = make_float4(acc[1][0], acc[1][1], acc[1][2], acc[1][3]);
        *(float4*)(nxt + (ra + 1) * DIM + c0 + 4) = make_float4(acc[1][4], acc[1][5], acc[1][6], acc[1][7]);
        __syncthreads();
        float4 xs[4];
        float mx = 0.f;
        {
            const float4* n4 = (const float4*)nxt;
#pragma unroll
            for (int j = 0; j < 4; j++) {
                float4 x = n4[t + 256 * j];
                xs[j] = x;
                mx = fmaxf(mx, fmaxf(fmaxf(fabsf(x.x), fabsf(x.y)),
                                     fmaxf(fabsf(x.z), fabsf(x.w))));
            }
        }
#pragma unroll
        for (int m = 1; m < 64; m <<= 1) mx = fmaxf(mx, __shfl_xor(mx, m));
        if (lane == 0) shRed[wave] = mx;
        __syncthreads();
        float gm = fmaxf(fmaxf(shRed[0], shRed[1]), fmaxf(shRed[2], shRed[3]));
        float inv = (gm > 0.f) ? (1.0f / gm) : 1.0f;
        {
            float4* n4 = (float4*)nxt;
#pragma unroll
            for (int j = 0; j < 4; j++) {
                float4 x = xs[j];
                n4[t + 256 * j] = make_float4(x.x * inv, x.y * inv, x.z * inv, x.w * inv);
            }
        }
        __syncthreads();
        float* tmp = cur; cur = nxt; nxt = tmp;
    }

    if (wave == 0) {
        float d = cur[lane * 65];
        float dmax = d;
#pragma unroll
        for (int m = 1; m < 64; m <<= 1) dmax = fmaxf(dmax, __shfl_xor(dmax, m));
        unsigned long long bal = __ballot(d == dmax);
        int jstar = __ffsll((long long)bal) - 1;
        shV[lane] = cur[jstar * DIM + lane];
    }
    __syncthreads();

    for (int it = 0; it < 8; it++) {
        float part = 0.f;
#pragma unroll
        for (int j = 0; j < 16; j++) {
            int k = wave * 16 + j;
            part = fmaf(cur[k * DIM + lane], shV[k], part);
        }
        shP[wave * DIM + lane] = part;
        __syncthreads();
        if (wave == 0)
            shV[lane] = shP[lane] + shP[64 + lane] + shP[128 + lane] + shP[192 + lane];
        __syncthreads();
    }

    if (wave == 0) {
        float val = shV[lane];
        float nn = val * val;
#pragma unroll
        for (int m = 1; m < 64; m <<= 1) nn += __shfl_xor(nn, m);
        float inv = (nn > 1e-30f) ? rsqrtf(nn) : 1.0f;
        float am = fabsf(val);
        float bm = am;
#pragma unroll
        for (int m = 1; m < 64; m <<= 1) bm = fmaxf(bm, __shfl_xor(bm, m));
        unsigned long long bal = __ballot(am == bm);
        int jm = __ffsll((long long)bal) - 1;
        float vm = __shfl(val, jm);
        float s = (vm < 0.f) ? -inv : inv;
        V[c * DIM + lane] = val * s;
    }
}

// ---------------- K4: given[i] = <feat_i, V[label_i]> ----------------
__global__ __launch_bounds__(256) void k_out(const float* __restrict__ feat,
                                             const int* __restrict__ label,
                                             const float* __restrict__ V,
                                             float* __restrict__ out, int n) {
    int i = blockIdx.x * blockDim.x + threadIdx.x;
    if (i >= n) return;
    const float4* rp = (const float4*)(feat + (size_t)i * DIM);
    const float4* vp = (const float4*)(V + label[i] * DIM);
    float s0 = 0, s1 = 0, s2 = 0, s3 = 0;
#pragma unroll
    for (int j = 0; j < 16; j++) {
        float4 a = rp[j], b = vp[j];
        s0 = fmaf(a.x, b.x, s0);
        s1 = fmaf(a.y, b.y, s1);
        s2 = fmaf(a.z, b.z, s2);
        s3 = fmaf(a.w, b.w, s3);
    }
    out[i] = (s0 + s1) + (s2 + s3);
}

extern "C" void kernel_launch(void* const* d_in, const int* in_sizes, int n_in,
                              void* d_out, int out_size, void* d_ws, size_t ws_size,
                              hipStream_t stream) {
    const float* feat  = (const float*)d_in[0];
    const int*   label = (const int*)d_in[1];
    const int    n     = in_sizes[1];
    float*       out   = (float*)d_out;

    int*   cnt    = (int*)d_ws;
    int*   base   = cnt + 16;
    int*   cursor = cnt + 32;
    float* G      = (float*)(cnt + 64);          // 16 * 4096 floats
    float* V      = G + NCLS * DIM * DIM;        // 16 * 64 floats
    int*   idx    = (int*)(V + NCLS * DIM);      // n ints

    k_init<<<64, 256, 0, stream>>>(cnt, G);
    k_hist<<<256, 256, 0, stream>>>(label, n, cnt);
    k_scan<<<1, 64, 0, stream>>>(cnt, base, cursor);
    k_scatter<<<256, 256, 0, stream>>>(label, n, cursor, idx);
    k_gram<<<NCLS * GBLK, 256, 0, stream>>>(feat, idx, base, cnt, G);
    k_eig<<<NCLS, 256, 0, stream>>>(G, V);
    k_out<<<(n + 255) / 256, 256, 0, stream>>>(feat, label, V, out, n);
}

// Round 7
// 441.054 us; speedup vs baseline: 2.3011x; 1.1783x over previous
//
#include <hip/hip_runtime.h>
#include <math.h>

#define NCLS 16
#define DIM  64
#define GBLK 48                 // 16*48 = 768 blocks = 256 CUs * 3 blocks/CU
#define QQ   4                  // rows per wave per iteration
#define STEP (4 * GBLK * QQ)    // 768 rows advanced per iteration per class

// ---------------- K1a: init counters + Gram buffer ----------------
__global__ void k_init(int* __restrict__ cnt, float* __restrict__ G) {
    int t = blockIdx.x * blockDim.x + threadIdx.x;
    if (t < NCLS) cnt[t] = 0;
    for (int i = t; i < NCLS * DIM * DIM; i += gridDim.x * blockDim.x) G[i] = 0.f;
}

// ---------------- K1b: class histogram ----------------
// Each thread: 8 consecutive labels via two int4 loads (independent,
// coalesced), then 8 sub-banked LDS atomics. No load->atomic dependent chain.
__global__ __launch_bounds__(256) void k_hist(const int* __restrict__ label,
                                              int n, int* __restrict__ cnt) {
    __shared__ int h[NCLS * 16];
    h[threadIdx.x] = 0;
    __syncthreads();
    const int sub = threadIdx.x & 15;
    const long i0 = (long)(blockIdx.x * 256 + threadIdx.x) * 8;
    if (i0 + 8 <= n) {
        int4 a = *(const int4*)(label + i0);
        int4 b = *(const int4*)(label + i0 + 4);
        atomicAdd(&h[a.x * 16 + sub], 1);
        atomicAdd(&h[a.y * 16 + sub], 1);
        atomicAdd(&h[a.z * 16 + sub], 1);
        atomicAdd(&h[a.w * 16 + sub], 1);
        atomicAdd(&h[b.x * 16 + sub], 1);
        atomicAdd(&h[b.y * 16 + sub], 1);
        atomicAdd(&h[b.z * 16 + sub], 1);
        atomicAdd(&h[b.w * 16 + sub], 1);
    } else {
        for (long i = i0; i < n; i++) atomicAdd(&h[label[i] * 16 + sub], 1);
    }
    __syncthreads();
    if (threadIdx.x < NCLS) {
        int s = 0;
#pragma unroll
        for (int j = 0; j < 16; j++) s += h[threadIdx.x * 16 + j];
        atomicAdd(&cnt[threadIdx.x], s);
    }
}

// ---------------- K1c: tiny exclusive scan (4-aligned bases) ----------------
// Bases aligned to 4 so k_gram can do int4 idx loads. Gaps between class
// segments are never read (gram reads only [base, base+cnt)).
__global__ void k_scan(const int* __restrict__ cnt, int* __restrict__ base,
                       int* __restrict__ cursor) {
    if (threadIdx.x == 0) {
        int s = 0;
        for (int c = 0; c < NCLS; c++) {
            base[c] = s; cursor[c] = s;
            s += (cnt[c] + 3) & ~3;
        }
    }
}

// ---------------- K1d: scatter row indices into class buckets ----------------
// Reservation stays at 16 global atomics/block to 16 DISTINCT words (R4's
// 65536-into-one-line variant cost 577 us). Within the block, 16 sub-cursors
// per class (LDS prefix over the sub-histogram) cut LDS atomic contention 16x.
__global__ __launch_bounds__(256) void k_scatter(const int* __restrict__ label,
                                                 int n, int* __restrict__ cursor,
                                                 int* __restrict__ idx) {
    __shared__ int h[NCLS * 16];
    __shared__ int cur[NCLS * 16];
    __shared__ int gb[NCLS];
    h[threadIdx.x] = 0;
    __syncthreads();
    const int sub = threadIdx.x & 15;
    const long i0 = (long)(blockIdx.x * 256 + threadIdx.x) * 8;
    int4 a, b;
    const bool full = (i0 + 8 <= n);
    if (full) {
        a = *(const int4*)(label + i0);
        b = *(const int4*)(label + i0 + 4);
        atomicAdd(&h[a.x * 16 + sub], 1);
        atomicAdd(&h[a.y * 16 + sub], 1);
        atomicAdd(&h[a.z * 16 + sub], 1);
        atomicAdd(&h[a.w * 16 + sub], 1);
        atomicAdd(&h[b.x * 16 + sub], 1);
        atomicAdd(&h[b.y * 16 + sub], 1);
        atomicAdd(&h[b.z * 16 + sub], 1);
        atomicAdd(&h[b.w * 16 + sub], 1);
    } else {
        for (long i = i0; i < n; i++) atomicAdd(&h[label[i] * 16 + sub], 1);
    }
    __syncthreads();
    // per-class exclusive prefix over 16 sub-counters (16 threads per class)
    {
        const int c = threadIdx.x >> 4, s = threadIdx.x & 15;
        int pre = 0;
        for (int j = 0; j < 16; j++) pre += (j < s) ? h[c * 16 + j] : 0;
        if (s == 15) gb[c] = atomicAdd(&cursor[c], pre + h[threadIdx.x]);
        __syncthreads();
        cur[threadIdx.x] = gb[c] + pre;
    }
    __syncthreads();
    if (full) {
        int p;
        p = atomicAdd(&cur[a.x * 16 + sub], 1); idx[p] = (int)i0 + 0;
        p = atomicAdd(&cur[a.y * 16 + sub], 1); idx[p] = (int)i0 + 1;
        p = atomicAdd(&cur[a.z * 16 + sub], 1); idx[p] = (int)i0 + 2;
        p = atomicAdd(&cur[a.w * 16 + sub], 1); idx[p] = (int)i0 + 3;
        p = atomicAdd(&cur[b.x * 16 + sub], 1); idx[p] = (int)i0 + 4;
        p = atomicAdd(&cur[b.y * 16 + sub], 1); idx[p] = (int)i0 + 5;
        p = atomicAdd(&cur[b.z * 16 + sub], 1); idx[p] = (int)i0 + 6;
        p = atomicAdd(&cur[b.w * 16 + sub], 1); idx[p] = (int)i0 + 7;
    } else {
        for (long i = i0; i < n; i++) {
            int p = atomicAdd(&cur[label[i] * 16 + sub], 1);
            idx[p] = (int)i;
        }
    }
}

// ---------------- K2: per-class Gram, branch-free main loop ----------------
// R6's hot loop stalled ~15K cyc/iter: the per-q if/else zeroing overwrote
// pending-load dest registers -> compiler emitted s_waitcnt vmcnt(0) per q,
// serializing the loads. Now: nfull unchecked iterations (unconditional int4
// idx prefetch -- idx is padded by STEP+16 ints and bases are 4-aligned --
// and 16 named float4 row loads), single checked tail outside the loop.
__global__ __launch_bounds__(256, 3) void k_gram(const float* __restrict__ feat,
                                                 const int* __restrict__ idx,
                                                 const int* __restrict__ base,
                                                 const int* __restrict__ cnt,
                                                 float* __restrict__ G) {
    const int c    = blockIdx.x & (NCLS - 1);
    const int blk  = blockIdx.x >> 4;          // 0..GBLK-1
    const int wave = threadIdx.x >> 6;
    const int lane = threadIdx.x & 63;
    const int gw   = blk * 4 + wave;           // 0..4*GBLK-1
    const int r0   = (lane >> 3) << 3;
    const int c0   = (lane & 7) << 3;
    const int m    = cnt[c];
    const int b0   = base[c];

    float acc[8][8];
#pragma unroll
    for (int j = 0; j < 8; j++)
#pragma unroll
        for (int k = 0; k < 8; k++) acc[j][k] = 0.f;

    const int p0 = gw * QQ;
    const int nfull = (m >= p0 + QQ) ? ((m - QQ - p0) / STEP + 1) : 0;

    const int* ip = idx + b0 + p0;
    int4 ii = *(const int4*)ip;                // always in-buffer (padded)

    for (int k = 0; k < nfull; k++) {
        ip += STEP;
        int4 iin = *(const int4*)ip;           // unconditional prefetch
        const float* q0 = feat + (size_t)ii.x * DIM;
        const float* q1 = feat + (size_t)ii.y * DIM;
        const float* q2 = feat + (size_t)ii.z * DIM;
        const float* q3 = feat + (size_t)ii.w * DIM;
        float4 xa0 = *(const float4*)(q0 + r0), ya0 = *(const float4*)(q0 + r0 + 4);
        float4 xb0 = *(const float4*)(q0 + c0), yb0 = *(const float4*)(q0 + c0 + 4);
        float4 xa1 = *(const float4*)(q1 + r0), ya1 = *(const float4*)(q1 + r0 + 4);
        float4 xb1 = *(const float4*)(q1 + c0), yb1 = *(const float4*)(q1 + c0 + 4);
        float4 xa2 = *(const float4*)(q2 + r0), ya2 = *(const float4*)(q2 + r0 + 4);
        float4 xb2 = *(const float4*)(q2 + c0), yb2 = *(const float4*)(q2 + c0 + 4);
        float4 xa3 = *(const float4*)(q3 + r0), ya3 = *(const float4*)(q3 + r0 + 4);
        float4 xb3 = *(const float4*)(q3 + c0), yb3 = *(const float4*)(q3 + c0 + 4);

#define FMA_Q(XA, YA, XB, YB)                                                   \
        {                                                                       \
            float av[8] = {XA.x, XA.y, XA.z, XA.w, YA.x, YA.y, YA.z, YA.w};     \
            float bv[8] = {XB.x, XB.y, XB.z, XB.w, YB.x, YB.y, YB.z, YB.w};     \
            _Pragma("unroll")                                                   \
            for (int j = 0; j < 8; j++)                                         \
                _Pragma("unroll")                                               \
                for (int kk = 0; kk < 8; kk++)                                  \
                    acc[j][kk] = fmaf(av[j], bv[kk], acc[j][kk]);               \
        }
        FMA_Q(xa0, ya0, xb0, yb0)
        FMA_Q(xa1, ya1, xb1, yb1)
        FMA_Q(xa2, ya2, xb2, yb2)
        FMA_Q(xa3, ya3, xb3, yb3)
        ii = iin;
    }

    // ---- checked tail: at most QQ rows, runs once ----
    const int pt = p0 + nfull * STEP;
#pragma unroll
    for (int q = 0; q < QQ; q++) {
        if (pt + q < m) {                      // wave-uniform
            int j = idx[b0 + pt + q];
            const float* rp = feat + (size_t)j * DIM;
            float4 xa = *(const float4*)(rp + r0), ya = *(const float4*)(rp + r0 + 4);
            float4 xb = *(const float4*)(rp + c0), yb = *(const float4*)(rp + c0 + 4);
            FMA_Q(xa, ya, xb, yb)
        }
    }
#undef FMA_Q

    // ---- phased LDS block reduction (race-free), then coalesced atomics ----
    __shared__ float tile[DIM * DIM];
    for (int w = 0; w < 4; w++) {
        if (wave == w) {
            float* t = tile + r0 * DIM + c0;
            if (w == 0) {
#pragma unroll
                for (int j = 0; j < 8; j++) {
                    *(float4*)(t + j * DIM)     = make_float4(acc[j][0], acc[j][1], acc[j][2], acc[j][3]);
                    *(float4*)(t + j * DIM + 4) = make_float4(acc[j][4], acc[j][5], acc[j][6], acc[j][7]);
                }
            } else {
#pragma unroll
                for (int j = 0; j < 8; j++) {
                    float4 u0 = *(float4*)(t + j * DIM);
                    float4 u1 = *(float4*)(t + j * DIM + 4);
                    u0.x += acc[j][0]; u0.y += acc[j][1]; u0.z += acc[j][2]; u0.w += acc[j][3];
                    u1.x += acc[j][4]; u1.y += acc[j][5]; u1.z += acc[j][6]; u1.w += acc[j][7];
                    *(float4*)(t + j * DIM)     = u0;
                    *(float4*)(t + j * DIM + 4) = u1;
                }
            }
        }
        __syncthreads();
    }
    float* g = G + c * DIM * DIM;
    for (int e = threadIdx.x; e < DIM * DIM; e += 256)
        atomicAdd(&g[e], tile[e]);
}

// ---------------- K3: top eigenvector per class (4-wave cooperative) ----
// (unchanged — validated: trace-moment shift, 7 LDS squarings to
// C=(G-sigma I)^128, column-of-max-diag start, 8 applies)
__global__ __launch_bounds__(256, 1) void k_eig(const float* __restrict__ G,
                                                float* __restrict__ V) {
    const int c    = blockIdx.x;
    const int t    = threadIdx.x;
    const int wave = t >> 6;
    const int lane = t & 63;
    __shared__ float shA[DIM * DIM];
    __shared__ float shB[DIM * DIM];
    __shared__ float shP[4 * DIM];
    __shared__ float shRed[4];
    __shared__ float shV[DIM];

    {
        const float4* g4 = (const float4*)(G + c * DIM * DIM);
        float4* a4 = (float4*)shA;
#pragma unroll
        for (int j = 0; j < 4; j++) a4[t + 256 * j] = g4[t + 256 * j];
    }
    __syncthreads();

    float ss = 0.f;
    {
        const float4* a4 = (const float4*)shA;
#pragma unroll
        for (int j = 0; j < 4; j++) {
            float4 x = a4[t + 256 * j];
            ss = fmaf(x.x, x.x, fmaf(x.y, x.y, fmaf(x.z, x.z, fmaf(x.w, x.w, ss))));
        }
    }
#pragma unroll
    for (int m = 1; m < 64; m <<= 1) ss += __shfl_xor(ss, m);
    if (lane == 0) shRed[wave] = ss;
    __syncthreads();
    if (wave == 0) {
        float s2 = shRed[0] + shRed[1] + shRed[2] + shRed[3];
        float d  = shA[lane * 65];
        float sd = d;
#pragma unroll
        for (int m = 1; m < 64; m <<= 1) sd += __shfl_xor(sd, m);
        float mu    = sd * (1.f / 64.f);
        float var   = fmaxf(s2 * (1.f / 64.f) - mu * mu, 0.f);
        float sigma = mu - 0.2f * sqrtf(var);
        shA[lane * 65] = d - sigma;
    }
    __syncthreads();

    float* cur = shA;
    float* nxt = shB;
    const int ra = wave * 16 + ((lane >> 3) << 1);
    const int c0 = (lane & 7) << 3;
    for (int sq = 0; sq < 7; sq++) {
        float acc[2][8];
#pragma unroll
        for (int j = 0; j < 8; j++) { acc[0][j] = 0.f; acc[1][j] = 0.f; }
#pragma unroll 4
        for (int k = 0; k < DIM; k++) {
            const float* rk = cur + k * DIM;
            float2 a2 = *(const float2*)(rk + ra);
            float4 b0 = *(const float4*)(rk + c0);
            float4 b1 = *(const float4*)(rk + c0 + 4);
            acc[0][0] = fmaf(a2.x, b0.x, acc[0][0]);
            acc[0][1] = fmaf(a2.x, b0.y, acc[0][1]);
            acc[0][2] = fmaf(a2.x, b0.z, acc[0][2]);
            acc[0][3] = fmaf(a2.x, b0.w, acc[0][3]);
            acc[0][4] = fmaf(a2.x, b1.x, acc[0][4]);
            acc[0][5] = fmaf(a2.x, b1.y, acc[0][5]);
            acc[0][6] = fmaf(a2.x, b1.z, acc[0][6]);
            acc[0][7] = fmaf(a2.x, b1.w, acc[0][7]);
            acc[1][0] = fmaf(a2.y, b0.x, acc[1][0]);
            acc[1][1] = fmaf(a2.y, b0.y, acc[1][1]);
            acc[1][2] = fmaf(a2.y, b0.z, acc[1][2]);
            acc[1][3] = fmaf(a2.y, b0.w, acc[1][3]);
            acc[1][4] = fmaf(a2.y, b1.x, acc[1][4]);
            acc[1][5] = fmaf(a2.y, b1.y, acc[1][5]);
            acc[1][6] = fmaf(a2.y, b1.z, acc[1][6]);
            acc[1][7] = fmaf(a2.y, b1.w, acc[1][7]);
        }
        *(float4*)(nxt + (ra + 0) * DIM + c0)     = make_float4(acc[0][0], acc[0][1], acc[0][2], acc[0][3]);
        *(float4*)(nxt + (ra + 0) * DIM + c0 + 4) = make_float4(acc[0][4], acc[0][5], acc[0][6], acc[0][7]);
        *(float4*)(nxt + (ra + 1) * DIM + c0)     = make_float4(acc[1][0], acc[1][1], acc[1][2], acc[1][3]);
        *(float4*)(nxt + (ra + 1) * DIM + c0 + 4) = make_float4(acc[1][4], acc[1][5], acc[1][6], acc[1][7]);
        __syncthreads();
        float4 xs[4];
        float mx = 0.f;
        {
            const float4* n4 = (const float4*)nxt;
#pragma unroll
            for (int j = 0; j < 4; j++) {
                float4 x = n4[t + 256 * j];
                xs[j] = x;
                mx = fmaxf(mx, fmaxf(fmaxf(fabsf(x.x), fabsf(x.y)),
                                     fmaxf(fabsf(x.z), fabsf(x.w))));
            }
        }
#pragma unroll
        for (int m = 1; m < 64; m <<= 1) mx = fmaxf(mx, __shfl_xor(mx, m));
        if (lane == 0) shRed[wave] = mx;
        __syncthreads();
        float gm = fmaxf(fmaxf(shRed[0], shRed[1]), fmaxf(shRed[2], shRed[3]));
        float inv = (gm > 0.f) ? (1.0f / gm) : 1.0f;
        {
            float4* n4 = (float4*)nxt;
#pragma unroll
            for (int j = 0; j < 4; j++) {
                float4 x = xs[j];
                n4[t + 256 * j] = make_float4(x.x * inv, x.y * inv, x.z * inv, x.w * inv);
            }
        }
        __syncthreads();
        float* tmp = cur; cur = nxt; nxt = tmp;
    }

    if (wave == 0) {
        float d = cur[lane * 65];
        float dmax = d;
#pragma unroll
        for (int m = 1; m < 64; m <<= 1) dmax = fmaxf(dmax, __shfl_xor(dmax, m));
        unsigned long long bal = __ballot(d == dmax);
        int jstar = __ffsll((long long)bal) - 1;
        shV[lane] = cur[jstar * DIM + lane];
    }
    __syncthreads();

    for (int it = 0; it < 8; it++) {
        float part = 0.f;
#pragma unroll
        for (int j = 0; j < 16; j++) {
            int k = wave * 16 + j;
            part = fmaf(cur[k * DIM + lane], shV[k], part);
        }
        shP[wave * DIM + lane] = part;
        __syncthreads();
        if (wave == 0)
            shV[lane] = shP[lane] + shP[64 + lane] + shP[128 + lane] + shP[192 + lane];
        __syncthreads();
    }

    if (wave == 0) {
        float val = shV[lane];
        float nn = val * val;
#pragma unroll
        for (int m = 1; m < 64; m <<= 1) nn += __shfl_xor(nn, m);
        float inv = (nn > 1e-30f) ? rsqrtf(nn) : 1.0f;
        float am = fabsf(val);
        float bm = am;
#pragma unroll
        for (int m = 1; m < 64; m <<= 1) bm = fmaxf(bm, __shfl_xor(bm, m));
        unsigned long long bal = __ballot(am == bm);
        int jm = __ffsll((long long)bal) - 1;
        float vm = __shfl(val, jm);
        float s = (vm < 0.f) ? -inv : inv;
        V[c * DIM + lane] = val * s;
    }
}

// ---------------- K4: given[i] = <feat_i, V[label_i]> ----------------
__global__ __launch_bounds__(256) void k_out(const float* __restrict__ feat,
                                             const int* __restrict__ label,
                                             const float* __restrict__ V,
                                             float* __restrict__ out, int n) {
    int i = blockIdx.x * blockDim.x + threadIdx.x;
    if (i >= n) return;
    const float4* rp = (const float4*)(feat + (size_t)i * DIM);
    const float4* vp = (const float4*)(V + label[i] * DIM);
    float s0 = 0, s1 = 0, s2 = 0, s3 = 0;
#pragma unroll
    for (int j = 0; j < 16; j++) {
        float4 a = rp[j], b = vp[j];
        s0 = fmaf(a.x, b.x, s0);
        s1 = fmaf(a.y, b.y, s1);
        s2 = fmaf(a.z, b.z, s2);
        s3 = fmaf(a.w, b.w, s3);
    }
    out[i] = (s0 + s1) + (s2 + s3);
}

extern "C" void kernel_launch(void* const* d_in, const int* in_sizes, int n_in,
                              void* d_out, int out_size, void* d_ws, size_t ws_size,
                              hipStream_t stream) {
    const float* feat  = (const float*)d_in[0];
    const int*   label = (const int*)d_in[1];
    const int    n     = in_sizes[1];
    float*       out   = (float*)d_out;

    // workspace layout (idx padded: +48 alignment slack, +STEP+16 prefetch)
    int*   cnt    = (int*)d_ws;
    int*   base   = cnt + 16;
    int*   cursor = cnt + 32;
    float* G      = (float*)(cnt + 64);          // 16 * 4096 floats
    float* V      = G + NCLS * DIM * DIM;        // 16 * 64 floats
    int*   idx    = (int*)(V + NCLS * DIM);      // n + 1024 ints

    const int hblocks = (n + 2047) / 2048;
    k_init<<<64, 256, 0, stream>>>(cnt, G);
    k_hist<<<hblocks, 256, 0, stream>>>(label, n, cnt);
    k_scan<<<1, 64, 0, stream>>>(cnt, base, cursor);
    k_scatter<<<hblocks, 256, 0, stream>>>(label, n, cursor, idx);
    k_gram<<<NCLS * GBLK, 256, 0, stream>>>(feat, idx, base, cnt, G);
    k_eig<<<NCLS, 256, 0, stream>>>(G, V);
    k_out<<<(n + 255) / 256, 256, 0, stream>>>(feat, label, V, out, n);
}

// Round 8
// 307.088 us; speedup vs baseline: 3.3050x; 1.4362x over previous
//
#include <hip/hip_runtime.h>
#include <math.h>

#define NCLS 16
#define DIM  64
#define GBLK 64                 // 16*64 = 1024 blocks = 256 CUs * 4 blocks/CU
#define QQ   4                  // rows per wave per iteration (1 KB stage)
#define STEP (4 * GBLK * QQ)    // 1024 rows advanced per iteration per class

// ---------------- K1: histogram partials + zero G ----------------
// Per-block LDS histogram (16x sub-banked) -> per-block partial counts in ws
// (no global atomics, no pre-zeroed cnt needed). Also grid-stride zeroes G.
__global__ __launch_bounds__(256) void k_hist(const int* __restrict__ label,
                                              int n, int* __restrict__ hpart,
                                              float* __restrict__ G) {
    __shared__ int h[NCLS * 16];
    h[threadIdx.x] = 0;
    for (int e = blockIdx.x * 256 + threadIdx.x; e < NCLS * DIM * DIM;
         e += gridDim.x * 256)
        G[e] = 0.f;
    __syncthreads();
    const int sub = threadIdx.x & 15;
    const long i0 = (long)(blockIdx.x * 256 + threadIdx.x) * 8;
    if (i0 + 8 <= n) {
        int4 a = *(const int4*)(label + i0);
        int4 b = *(const int4*)(label + i0 + 4);
        atomicAdd(&h[a.x * 16 + sub], 1);
        atomicAdd(&h[a.y * 16 + sub], 1);
        atomicAdd(&h[a.z * 16 + sub], 1);
        atomicAdd(&h[a.w * 16 + sub], 1);
        atomicAdd(&h[b.x * 16 + sub], 1);
        atomicAdd(&h[b.y * 16 + sub], 1);
        atomicAdd(&h[b.z * 16 + sub], 1);
        atomicAdd(&h[b.w * 16 + sub], 1);
    } else {
        for (long i = i0; i < n; i++) atomicAdd(&h[label[i] * 16 + sub], 1);
    }
    __syncthreads();
    if (threadIdx.x < NCLS) {
        int s = 0;
#pragma unroll
        for (int j = 0; j < 16; j++) s += h[threadIdx.x * 16 + j];
        hpart[blockIdx.x * 16 + threadIdx.x] = s;
    }
}

// ---------------- K2: sum partials + exclusive scan (4-aligned bases) -------
__global__ void k_scan(const int* __restrict__ hpart, int nb,
                       int* __restrict__ cnt, int* __restrict__ base,
                       int* __restrict__ cursor) {
    __shared__ int ph[64];
    __shared__ int sc[16];
    const int t = threadIdx.x;            // 64 threads
    const int c = t & 15, part = t >> 4;
    const int nb4 = (nb + 3) >> 2;
    int s = 0;
    for (int b = part * nb4; b < nb && b < (part + 1) * nb4; b++)
        s += hpart[b * 16 + c];
    ph[t] = s;
    __syncthreads();
    if (t < 16) {
        int tot = ph[t] + ph[16 + t] + ph[32 + t] + ph[48 + t];
        sc[t] = tot;
        cnt[t] = tot;
    }
    __syncthreads();
    if (t < 16) {
        int pre = 0;
        for (int j = 0; j < t; j++) pre += (sc[j] + 3) & ~3;
        base[t] = pre;
        cursor[t] = pre;
    }
}

// ---------------- K3: scatter row indices into class buckets ----------------
// Reservation = 16 global atomics/block to 16 DISTINCT words (R4 lesson);
// 16 sub-cursors per class via LDS prefix cut LDS-atomic contention 16x.
__global__ __launch_bounds__(256) void k_scatter(const int* __restrict__ label,
                                                 int n, int* __restrict__ cursor,
                                                 int* __restrict__ idx) {
    __shared__ int h[NCLS * 16];
    __shared__ int cur[NCLS * 16];
    __shared__ int gb[NCLS];
    h[threadIdx.x] = 0;
    __syncthreads();
    const int sub = threadIdx.x & 15;
    const long i0 = (long)(blockIdx.x * 256 + threadIdx.x) * 8;
    int4 a, b;
    const bool full = (i0 + 8 <= n);
    if (full) {
        a = *(const int4*)(label + i0);
        b = *(const int4*)(label + i0 + 4);
        atomicAdd(&h[a.x * 16 + sub], 1);
        atomicAdd(&h[a.y * 16 + sub], 1);
        atomicAdd(&h[a.z * 16 + sub], 1);
        atomicAdd(&h[a.w * 16 + sub], 1);
        atomicAdd(&h[b.x * 16 + sub], 1);
        atomicAdd(&h[b.y * 16 + sub], 1);
        atomicAdd(&h[b.z * 16 + sub], 1);
        atomicAdd(&h[b.w * 16 + sub], 1);
    } else {
        for (long i = i0; i < n; i++) atomicAdd(&h[label[i] * 16 + sub], 1);
    }
    __syncthreads();
    {
        const int c = threadIdx.x >> 4, s = threadIdx.x & 15;
        int pre = 0;
        for (int j = 0; j < 16; j++) pre += (j < s) ? h[c * 16 + j] : 0;
        if (s == 15) gb[c] = atomicAdd(&cursor[c], pre + h[threadIdx.x]);
        __syncthreads();
        cur[threadIdx.x] = gb[c] + pre;
    }
    __syncthreads();
    if (full) {
        int p;
        p = atomicAdd(&cur[a.x * 16 + sub], 1); idx[p] = (int)i0 + 0;
        p = atomicAdd(&cur[a.y * 16 + sub], 1); idx[p] = (int)i0 + 1;
        p = atomicAdd(&cur[a.z * 16 + sub], 1); idx[p] = (int)i0 + 2;
        p = atomicAdd(&cur[a.w * 16 + sub], 1); idx[p] = (int)i0 + 3;
        p = atomicAdd(&cur[b.x * 16 + sub], 1); idx[p] = (int)i0 + 4;
        p = atomicAdd(&cur[b.y * 16 + sub], 1); idx[p] = (int)i0 + 5;
        p = atomicAdd(&cur[b.z * 16 + sub], 1); idx[p] = (int)i0 + 6;
        p = atomicAdd(&cur[b.w * 16 + sub], 1); idx[p] = (int)i0 + 7;
    } else {
        for (long i = i0; i < n; i++) {
            int p = atomicAdd(&cur[label[i] * 16 + sub], 1);
            idx[p] = (int)i;
        }
    }
}

// ---------------- K4: per-class Gram via LDS-staged gather ----------------
// R7 was latency-serialized: only 56 arch VGPRs -> the 16 float4 load dests
// couldn't all be in flight -> ~4 vmcnt drains/iter. Now rows are staged with
// global_load_lds (dest = wave-uniform LDS base + lane*16B; one instruction
// stages 4 rows of 256 B), wave-private DOUBLE-BUFFERED (no barrier in loop):
//   issue idx(k+2) prefetch; clamp idx(k+1) (loaded last iter -> no stall);
//   issue stage(k+1); s_waitcnt vmcnt(2) (drains stage(k)); compute group k
//   from LDS (ds_read_b128, 2-way bank alias = free).
// A- and B-fragments both read from the staged row -> global traffic halves
// (each row fetched once: 128 MB total). acc stays in unified-file AGPRs.
__global__ __launch_bounds__(256, 4) void k_gram(const float* __restrict__ feat,
                                                 const int* __restrict__ idx,
                                                 const int* __restrict__ base,
                                                 const int* __restrict__ cnt,
                                                 float* __restrict__ G,
                                                 int nrows) {
    const int c    = blockIdx.x & (NCLS - 1);
    const int blk  = blockIdx.x >> 4;          // 0..GBLK-1
    const int wave = threadIdx.x >> 6;
    const int lane = threadIdx.x & 63;
    const int gw   = blk * 4 + wave;           // 0..4*GBLK-1
    const int r0   = (lane >> 3) << 3;
    const int c0   = (lane & 7) << 3;
    const int m    = cnt[c];
    const int b0   = base[c];

    __shared__ float stage[4 * 2 * 256];       // 4 waves x 2 bufs x 1 KB
    float* st = stage + wave * 512;

    float acc[8][8];
#pragma unroll
    for (int j = 0; j < 8; j++)
#pragma unroll
        for (int k = 0; k < 8; k++) acc[j][k] = 0.f;

    const int p0    = gw * QQ;
    const int nfull = (m >= p0 + QQ) ? ((m - QQ - p0) / STEP + 1) : 0;
    const int sr    = lane >> 4;               // row slot 0..3
    const int sc16  = lane & 15;               // 16-B segment within row
    const int* ipp  = idx + b0 + p0 + sr;      // this lane's idx stream

#define STAGE(ROW, DSTF)                                                        \
    __builtin_amdgcn_global_load_lds(                                           \
        (const __attribute__((address_space(1))) void*)(feat + (size_t)(ROW) * DIM + sc16 * 4), \
        (__attribute__((address_space(3))) void*)((DSTF)), 16, 0, 0)

    int i_nxt_raw = 0;
    if (nfull > 0) {
        int i0r = ipp[0];                      // in-range for full group 0
        STAGE(i0r, st);                        // S(0) -> buf 0
        i_nxt_raw = ipp[STEP];                 // idx(1), may be pad
    }

    for (int k = 0; k < nfull; k++) {
        const int buf = (k & 1) << 8;          // 0 or 256 floats
        int i_fut_raw = ipp[(size_t)(k + 2) * STEP];   // prefetch, NOT used yet
        int i_n = ((unsigned)i_nxt_raw < (unsigned)nrows) ? i_nxt_raw : 0;
        STAGE(i_n, st + (buf ^ 256));          // S(k+1) -> other buf
        asm volatile("s_waitcnt vmcnt(2)" ::: "memory");   // S(k) done
        const float* sb = st + buf;
#pragma unroll
        for (int q = 0; q < QQ; q++) {
            float4 a0 = *(const float4*)(sb + q * 64 + r0);
            float4 a1 = *(const float4*)(sb + q * 64 + r0 + 4);
            float4 bb0 = *(const float4*)(sb + q * 64 + c0);
            float4 bb1 = *(const float4*)(sb + q * 64 + c0 + 4);
            float av[8] = {a0.x, a0.y, a0.z, a0.w, a1.x, a1.y, a1.z, a1.w};
            float bv[8] = {bb0.x, bb0.y, bb0.z, bb0.w, bb1.x, bb1.y, bb1.z, bb1.w};
#pragma unroll
            for (int j = 0; j < 8; j++)
#pragma unroll
                for (int kk = 0; kk < 8; kk++)
                    acc[j][kk] = fmaf(av[j], bv[kk], acc[j][kk]);
        }
        i_nxt_raw = i_fut_raw;
    }
    asm volatile("s_waitcnt vmcnt(0)" ::: "memory");
#undef STAGE

    // ---- checked tail: at most QQ rows, register gather, runs once ----
    const int pt = p0 + nfull * STEP;
#pragma unroll
    for (int q = 0; q < QQ; q++) {
        if (pt + q < m) {                      // wave-uniform
            int jrow = idx[b0 + pt + q];
            const float* rp = feat + (size_t)jrow * DIM;
            float4 a0 = *(const float4*)(rp + r0), a1 = *(const float4*)(rp + r0 + 4);
            float4 bb0 = *(const float4*)(rp + c0), bb1 = *(const float4*)(rp + c0 + 4);
            float av[8] = {a0.x, a0.y, a0.z, a0.w, a1.x, a1.y, a1.z, a1.w};
            float bv[8] = {bb0.x, bb0.y, bb0.z, bb0.w, bb1.x, bb1.y, bb1.z, bb1.w};
#pragma unroll
            for (int j = 0; j < 8; j++)
#pragma unroll
                for (int kk = 0; kk < 8; kk++)
                    acc[j][kk] = fmaf(av[j], bv[kk], acc[j][kk]);
        }
    }

    // ---- phased LDS block reduction (race-free), then coalesced atomics ----
    __shared__ float tile[DIM * DIM];
    for (int w = 0; w < 4; w++) {
        if (wave == w) {
            float* t = tile + r0 * DIM + c0;
            if (w == 0) {
#pragma unroll
                for (int j = 0; j < 8; j++) {
                    *(float4*)(t + j * DIM)     = make_float4(acc[j][0], acc[j][1], acc[j][2], acc[j][3]);
                    *(float4*)(t + j * DIM + 4) = make_float4(acc[j][4], acc[j][5], acc[j][6], acc[j][7]);
                }
            } else {
#pragma unroll
                for (int j = 0; j < 8; j++) {
                    float4 u0 = *(float4*)(t + j * DIM);
                    float4 u1 = *(float4*)(t + j * DIM + 4);
                    u0.x += acc[j][0]; u0.y += acc[j][1]; u0.z += acc[j][2]; u0.w += acc[j][3];
                    u1.x += acc[j][4]; u1.y += acc[j][5]; u1.z += acc[j][6]; u1.w += acc[j][7];
                    *(float4*)(t + j * DIM)     = u0;
                    *(float4*)(t + j * DIM + 4) = u1;
                }
            }
        }
        __syncthreads();
    }
    float* g = G + c * DIM * DIM;
    for (int e = threadIdx.x; e < DIM * DIM; e += 256)
        atomicAdd(&g[e], tile[e]);
}

// ---------------- K5: top eigenvector per class (4-wave cooperative) ----
// (unchanged — validated: trace-moment shift, 7 LDS squarings to
// C=(G-sigma I)^128, column-of-max-diag start, 8 applies)
__global__ __launch_bounds__(256, 1) void k_eig(const float* __restrict__ G,
                                                float* __restrict__ V) {
    const int c    = blockIdx.x;
    const int t    = threadIdx.x;
    const int wave = t >> 6;
    const int lane = t & 63;
    __shared__ float shA[DIM * DIM];
    __shared__ float shB[DIM * DIM];
    __shared__ float shP[4 * DIM];
    __shared__ float shRed[4];
    __shared__ float shV[DIM];

    {
        const float4* g4 = (const float4*)(G + c * DIM * DIM);
        float4* a4 = (float4*)shA;
#pragma unroll
        for (int j = 0; j < 4; j++) a4[t + 256 * j] = g4[t + 256 * j];
    }
    __syncthreads();

    float ss = 0.f;
    {
        const float4* a4 = (const float4*)shA;
#pragma unroll
        for (int j = 0; j < 4; j++) {
            float4 x = a4[t + 256 * j];
            ss = fmaf(x.x, x.x, fmaf(x.y, x.y, fmaf(x.z, x.z, fmaf(x.w, x.w, ss))));
        }
    }
#pragma unroll
    for (int m = 1; m < 64; m <<= 1) ss += __shfl_xor(ss, m);
    if (lane == 0) shRed[wave] = ss;
    __syncthreads();
    if (wave == 0) {
        float s2 = shRed[0] + shRed[1] + shRed[2] + shRed[3];
        float d  = shA[lane * 65];
        float sd = d;
#pragma unroll
        for (int m = 1; m < 64; m <<= 1) sd += __shfl_xor(sd, m);
        float mu    = sd * (1.f / 64.f);
        float var   = fmaxf(s2 * (1.f / 64.f) - mu * mu, 0.f);
        float sigma = mu - 0.2f * sqrtf(var);
        shA[lane * 65] = d - sigma;
    }
    __syncthreads();

    float* cur = shA;
    float* nxt = shB;
    const int ra = wave * 16 + ((lane >> 3) << 1);
    const int c0 = (lane & 7) << 3;
    for (int sq = 0; sq < 7; sq++) {
        float acc[2][8];
#pragma unroll
        for (int j = 0; j < 8; j++) { acc[0][j] = 0.f; acc[1][j] = 0.f; }
#pragma unroll 4
        for (int k = 0; k < DIM; k++) {
            const float* rk = cur + k * DIM;
            float2 a2 = *(const float2*)(rk + ra);
            float4 b0 = *(const float4*)(rk + c0);
            float4 b1 = *(const float4*)(rk + c0 + 4);
            acc[0][0] = fmaf(a2.x, b0.x, acc[0][0]);
            acc[0][1] = fmaf(a2.x, b0.y, acc[0][1]);
            acc[0][2] = fmaf(a2.x, b0.z, acc[0][2]);
            acc[0][3] = fmaf(a2.x, b0.w, acc[0][3]);
            acc[0][4] = fmaf(a2.x, b1.x, acc[0][4]);
            acc[0][5] = fmaf(a2.x, b1.y, acc[0][5]);
            acc[0][6] = fmaf(a2.x, b1.z, acc[0][6]);
            acc[0][7] = fmaf(a2.x, b1.w, acc[0][7]);
            acc[1][0] = fmaf(a2.y, b0.x, acc[1][0]);
            acc[1][1] = fmaf(a2.y, b0.y, acc[1][1]);
            acc[1][2] = fmaf(a2.y, b0.z, acc[1][2]);
            acc[1][3] = fmaf(a2.y, b0.w, acc[1][3]);
            acc[1][4] = fmaf(a2.y, b1.x, acc[1][4]);
            acc[1][5] = fmaf(a2.y, b1.y, acc[1][5]);
            acc[1][6] = fmaf(a2.y, b1.z, acc[1][6]);
            acc[1][7] = fmaf(a2.y, b1.w, acc[1][7]);
        }
        *(float4*)(nxt + (ra + 0) * DIM + c0)     = make_float4(acc[0][0], acc[0][1], acc[0][2], acc[0][3]);
        *(float4*)(nxt + (ra + 0) * DIM + c0 + 4) = make_float4(acc[0][4], acc[0][5], acc[0][6], acc[0][7]);
        *(float4*)(nxt + (ra + 1) * DIM + c0)     = make_float4(acc[1][0], acc[1][1], acc[1][2], acc[1][3]);
        *(float4*)(nxt + (ra + 1) * DIM + c0 + 4) = make_float4(acc[1][4], acc[1][5], acc[1][6], acc[1][7]);
        __syncthreads();
        float4 xs[4];
        float mx = 0.f;
        {
            const float4* n4 = (const float4*)nxt;
#pragma unroll
            for (int j = 0; j < 4; j++) {
                float4 x = n4[t + 256 * j];
                xs[j] = x;
                mx = fmaxf(mx, fmaxf(fmaxf(fabsf(x.x), fabsf(x.y)),
                                     fmaxf(fabsf(x.z), fabsf(x.w))));
            }
        }
#pragma unroll
        for (int m = 1; m < 64; m <<= 1) mx = fmaxf(mx, __shfl_xor(mx, m));
        if (lane == 0) shRed[wave] = mx;
        __syncthreads();
        float gm = fmaxf(fmaxf(shRed[0], shRed[1]), fmaxf(shRed[2], shRed[3]));
        float inv = (gm > 0.f) ? (1.0f / gm) : 1.0f;
        {
            float4* n4 = (float4*)nxt;
#pragma unroll
            for (int j = 0; j < 4; j++) {
                float4 x = xs[j];
                n4[t + 256 * j] = make_float4(x.x * inv, x.y * inv, x.z * inv, x.w * inv);
            }
        }
        __syncthreads();
        float* tmp = cur; cur = nxt; nxt = tmp;
    }

    if (wave == 0) {
        float d = cur[lane * 65];
        float dmax = d;
#pragma unroll
        for (int m = 1; m < 64; m <<= 1) dmax = fmaxf(dmax, __shfl_xor(dmax, m));
        unsigned long long bal = __ballot(d == dmax);
        int jstar = __ffsll((long long)bal) - 1;
        shV[lane] = cur[jstar * DIM + lane];
    }
    __syncthreads();

    for (int it = 0; it < 8; it++) {
        float part = 0.f;
#pragma unroll
        for (int j = 0; j < 16; j++) {
            int k = wave * 16 + j;
            part = fmaf(cur[k * DIM + lane], shV[k], part);
        }
        shP[wave * DIM + lane] = part;
        __syncthreads();
        if (wave == 0)
            shV[lane] = shP[lane] + shP[64 + lane] + shP[128 + lane] + shP[192 + lane];
        __syncthreads();
    }

    if (wave == 0) {
        float val = shV[lane];
        float nn = val * val;
#pragma unroll
        for (int m = 1; m < 64; m <<= 1) nn += __shfl_xor(nn, m);
        float inv = (nn > 1e-30f) ? rsqrtf(nn) : 1.0f;
        float am = fabsf(val);
        float bm = am;
#pragma unroll
        for (int m = 1; m < 64; m <<= 1) bm = fmaxf(bm, __shfl_xor(bm, m));
        unsigned long long bal = __ballot(am == bm);
        int jm = __ffsll((long long)bal) - 1;
        float vm = __shfl(val, jm);
        float s = (vm < 0.f) ? -inv : inv;
        V[c * DIM + lane] = val * s;
    }
}

// ---------------- K6: given[i] = <feat_i, V[label_i]> ----------------
__global__ __launch_bounds__(256) void k_out(const float* __restrict__ feat,
                                             const int* __restrict__ label,
                                             const float* __restrict__ V,
                                             float* __restrict__ out, int n) {
    int i = blockIdx.x * blockDim.x + threadIdx.x;
    if (i >= n) return;
    const float4* rp = (const float4*)(feat + (size_t)i * DIM);
    const float4* vp = (const float4*)(V + label[i] * DIM);
    float s0 = 0, s1 = 0, s2 = 0, s3 = 0;
#pragma unroll
    for (int j = 0; j < 16; j++) {
        float4 a = rp[j], b = vp[j];
        s0 = fmaf(a.x, b.x, s0);
        s1 = fmaf(a.y, b.y, s1);
        s2 = fmaf(a.z, b.z, s2);
        s3 = fmaf(a.w, b.w, s3);
    }
    out[i] = (s0 + s1) + (s2 + s3);
}

extern "C" void kernel_launch(void* const* d_in, const int* in_sizes, int n_in,
                              void* d_out, int out_size, void* d_ws, size_t ws_size,
                              hipStream_t stream) {
    const float* feat  = (const float*)d_in[0];
    const int*   label = (const int*)d_in[1];
    const int    n     = in_sizes[1];
    float*       out   = (float*)d_out;

    // workspace layout (~2.4 MB); idx padded by 4096 ints for the
    // always-in-buffer prefetch (reads up to ~2.1K past the last class).
    int*   wsi    = (int*)d_ws;
    int*   cnt    = wsi;                         // 16
    int*   base   = wsi + 16;                    // 16
    int*   cursor = wsi + 32;                    // 16
    int*   hpart  = wsi + 48;                    // up to 4096
    float* G      = (float*)(wsi + 4160);        // 16*4096 floats (16-B aligned)
    float* V      = G + NCLS * DIM * DIM;        // 16*64 floats
    int*   idx    = (int*)(V + NCLS * DIM);      // n + 4096 ints

    const int hblocks = (n + 2047) / 2048;       // 256 at n=524288
    k_hist<<<hblocks, 256, 0, stream>>>(label, n, hpart, G);
    k_scan<<<1, 64, 0, stream>>>(hpart, hblocks, cnt, base, cursor);
    k_scatter<<<hblocks, 256, 0, stream>>>(label, n, cursor, idx);
    k_gram<<<NCLS * GBLK, 256, 0, stream>>>(feat, idx, base, cnt, G, n);
    k_eig<<<NCLS, 256, 0, stream>>>(G, V);
    k_out<<<(n + 255) / 256, 256, 0, stream>>>(feat, label, V, out, n);
}

// Round 9
// 303.688 us; speedup vs baseline: 3.3420x; 1.0112x over previous
//
#include <hip/hip_runtime.h>
#include <math.h>

#define NCLS 16
#define DIM  64
#define GBLK 64                 // 16*64 = 1024 blocks = 256 CUs * 4 blocks/CU
#define QQ   8                  // rows per wave per iteration (2 KB stage)
#define STEP (4 * GBLK * QQ)    // 2048 rows advanced per iteration per class

// ---------------- K1: histogram partials + zero G ----------------
__global__ __launch_bounds__(256) void k_hist(const int* __restrict__ label,
                                              int n, int* __restrict__ hpart,
                                              float* __restrict__ G) {
    __shared__ int h[NCLS * 16];
    h[threadIdx.x] = 0;
    for (int e = blockIdx.x * 256 + threadIdx.x; e < NCLS * DIM * DIM;
         e += gridDim.x * 256)
        G[e] = 0.f;
    __syncthreads();
    const int sub = threadIdx.x & 15;
    const long i0 = (long)(blockIdx.x * 256 + threadIdx.x) * 8;
    if (i0 + 8 <= n) {
        int4 a = *(const int4*)(label + i0);
        int4 b = *(const int4*)(label + i0 + 4);
        atomicAdd(&h[a.x * 16 + sub], 1);
        atomicAdd(&h[a.y * 16 + sub], 1);
        atomicAdd(&h[a.z * 16 + sub], 1);
        atomicAdd(&h[a.w * 16 + sub], 1);
        atomicAdd(&h[b.x * 16 + sub], 1);
        atomicAdd(&h[b.y * 16 + sub], 1);
        atomicAdd(&h[b.z * 16 + sub], 1);
        atomicAdd(&h[b.w * 16 + sub], 1);
    } else {
        for (long i = i0; i < n; i++) atomicAdd(&h[label[i] * 16 + sub], 1);
    }
    __syncthreads();
    if (threadIdx.x < NCLS) {
        int s = 0;
#pragma unroll
        for (int j = 0; j < 16; j++) s += h[threadIdx.x * 16 + j];
        hpart[blockIdx.x * 16 + threadIdx.x] = s;
    }
}

// ---------------- K2: sum partials + exclusive scan (4-aligned bases) -------
__global__ void k_scan(const int* __restrict__ hpart, int nb,
                       int* __restrict__ cnt, int* __restrict__ base,
                       int* __restrict__ cursor) {
    __shared__ int ph[64];
    __shared__ int sc[16];
    const int t = threadIdx.x;            // 64 threads
    const int c = t & 15, part = t >> 4;
    const int nb4 = (nb + 3) >> 2;
    int s = 0;
    for (int b = part * nb4; b < nb && b < (part + 1) * nb4; b++)
        s += hpart[b * 16 + c];
    ph[t] = s;
    __syncthreads();
    if (t < 16) {
        int tot = ph[t] + ph[16 + t] + ph[32 + t] + ph[48 + t];
        sc[t] = tot;
        cnt[t] = tot;
    }
    __syncthreads();
    if (t < 16) {
        int pre = 0;
        for (int j = 0; j < t; j++) pre += (sc[j] + 3) & ~3;
        base[t] = pre;
        cursor[t] = pre;
    }
}

// ---------------- K3: scatter row indices into class buckets ----------------
// Reservation = 16 global atomics/block to 16 DISTINCT words (R4 lesson);
// 16 sub-cursors per class via LDS prefix cut LDS-atomic contention 16x.
__global__ __launch_bounds__(256) void k_scatter(const int* __restrict__ label,
                                                 int n, int* __restrict__ cursor,
                                                 int* __restrict__ idx) {
    __shared__ int h[NCLS * 16];
    __shared__ int cur[NCLS * 16];
    __shared__ int gb[NCLS];
    h[threadIdx.x] = 0;
    __syncthreads();
    const int sub = threadIdx.x & 15;
    const long i0 = (long)(blockIdx.x * 256 + threadIdx.x) * 8;
    int4 a, b;
    const bool full = (i0 + 8 <= n);
    if (full) {
        a = *(const int4*)(label + i0);
        b = *(const int4*)(label + i0 + 4);
        atomicAdd(&h[a.x * 16 + sub], 1);
        atomicAdd(&h[a.y * 16 + sub], 1);
        atomicAdd(&h[a.z * 16 + sub], 1);
        atomicAdd(&h[a.w * 16 + sub], 1);
        atomicAdd(&h[b.x * 16 + sub], 1);
        atomicAdd(&h[b.y * 16 + sub], 1);
        atomicAdd(&h[b.z * 16 + sub], 1);
        atomicAdd(&h[b.w * 16 + sub], 1);
    } else {
        for (long i = i0; i < n; i++) atomicAdd(&h[label[i] * 16 + sub], 1);
    }
    __syncthreads();
    {
        const int c = threadIdx.x >> 4, s = threadIdx.x & 15;
        int pre = 0;
        for (int j = 0; j < 16; j++) pre += (j < s) ? h[c * 16 + j] : 0;
        if (s == 15) gb[c] = atomicAdd(&cursor[c], pre + h[threadIdx.x]);
        __syncthreads();
        cur[threadIdx.x] = gb[c] + pre;
    }
    __syncthreads();
    if (full) {
        int p;
        p = atomicAdd(&cur[a.x * 16 + sub], 1); idx[p] = (int)i0 + 0;
        p = atomicAdd(&cur[a.y * 16 + sub], 1); idx[p] = (int)i0 + 1;
        p = atomicAdd(&cur[a.z * 16 + sub], 1); idx[p] = (int)i0 + 2;
        p = atomicAdd(&cur[a.w * 16 + sub], 1); idx[p] = (int)i0 + 3;
        p = atomicAdd(&cur[b.x * 16 + sub], 1); idx[p] = (int)i0 + 4;
        p = atomicAdd(&cur[b.y * 16 + sub], 1); idx[p] = (int)i0 + 5;
        p = atomicAdd(&cur[b.z * 16 + sub], 1); idx[p] = (int)i0 + 6;
        p = atomicAdd(&cur[b.w * 16 + sub], 1); idx[p] = (int)i0 + 7;
    } else {
        for (long i = i0; i < n; i++) {
            int p = atomicAdd(&cur[label[i] * 16 + sub], 1);
            idx[p] = (int)i;
        }
    }
}

// ---------------- K4: per-class Gram via LDS-staged gather (QQ=8) ----------
// Rows staged with global_load_lds (one instr stages 4 rows: lane->base+16B),
// two instrs per 8-row group, wave-private double-buffered, no barrier in the
// loop. Per iteration: idx(k+2) prefetch (2 b32), stage(k+1) (2 vm),
// s_waitcnt vmcnt(4) (drains stage(k)), then 512 fmas from LDS. 1024 issue-cyc
// of fma per wave per stage round-trip x 4 waves/SIMD >> 900-cyc HBM latency.
__global__ __launch_bounds__(256, 4) void k_gram(const float* __restrict__ feat,
                                                 const int* __restrict__ idx,
                                                 const int* __restrict__ base,
                                                 const int* __restrict__ cnt,
                                                 float* __restrict__ G,
                                                 int nrows) {
    const int c    = blockIdx.x & (NCLS - 1);
    const int blk  = blockIdx.x >> 4;          // 0..GBLK-1
    const int wave = threadIdx.x >> 6;
    const int lane = threadIdx.x & 63;
    const int gw   = blk * 4 + wave;           // 0..4*GBLK-1
    const int r0   = (lane >> 3) << 3;
    const int c0   = (lane & 7) << 3;
    const int m    = cnt[c];
    const int b0   = base[c];

    __shared__ float stage[4 * 2 * 512];       // 4 waves x 2 bufs x 2 KB
    float* st = stage + wave * 1024;

    float acc[8][8];
#pragma unroll
    for (int j = 0; j < 8; j++)
#pragma unroll
        for (int k = 0; k < 8; k++) acc[j][k] = 0.f;

    const int p0    = gw * QQ;
    const int nfull = (m >= p0 + QQ) ? ((m - QQ - p0) / STEP + 1) : 0;
    const int sr    = lane >> 4;               // row slot 0..3
    const int sc16  = lane & 15;               // 16-B segment within row
    const int* ippA = idx + b0 + p0 + sr;      // rows 0..3 of the group
    const int* ippB = ippA + 4;                // rows 4..7 of the group

#define STAGE(ROW, DSTF)                                                        \
    __builtin_amdgcn_global_load_lds(                                           \
        (const __attribute__((address_space(1))) void*)(feat + (size_t)(ROW) * DIM + sc16 * 4), \
        (__attribute__((address_space(3))) void*)((DSTF)), 16, 0, 0)

    int inA = 0, inB = 0;
    if (nfull > 0) {
        int a0 = ippA[0], b0r = ippB[0];       // in-range for full group 0
        STAGE(a0, st);                         // S(0) rows 0-3 -> buf 0
        STAGE(b0r, st + 256);                  // S(0) rows 4-7
        inA = ippA[STEP];                      // idx(1), may be pad
        inB = ippB[STEP];
    }

    for (int k = 0; k < nfull; k++) {
        const int buf = (k & 1) << 9;          // 0 or 512 floats
        int ifA = ippA[(size_t)(k + 2) * STEP];        // prefetch, NOT used yet
        int ifB = ippB[(size_t)(k + 2) * STEP];
        int nA = ((unsigned)inA < (unsigned)nrows) ? inA : 0;
        int nB = ((unsigned)inB < (unsigned)nrows) ? inB : 0;
        float* ob = st + (buf ^ 512);
        STAGE(nA, ob);                         // S(k+1) -> other buf
        STAGE(nB, ob + 256);
        asm volatile("s_waitcnt vmcnt(4)" ::: "memory");   // S(k) done
        const float* sb = st + buf;
#pragma unroll
        for (int q = 0; q < QQ; q++) {
            float4 a0 = *(const float4*)(sb + q * 64 + r0);
            float4 a1 = *(const float4*)(sb + q * 64 + r0 + 4);
            float4 bb0 = *(const float4*)(sb + q * 64 + c0);
            float4 bb1 = *(const float4*)(sb + q * 64 + c0 + 4);
            float av[8] = {a0.x, a0.y, a0.z, a0.w, a1.x, a1.y, a1.z, a1.w};
            float bv[8] = {bb0.x, bb0.y, bb0.z, bb0.w, bb1.x, bb1.y, bb1.z, bb1.w};
#pragma unroll
            for (int j = 0; j < 8; j++)
#pragma unroll
                for (int kk = 0; kk < 8; kk++)
                    acc[j][kk] = fmaf(av[j], bv[kk], acc[j][kk]);
        }
        inA = ifA; inB = ifB;
    }
    asm volatile("s_waitcnt vmcnt(0)" ::: "memory");
#undef STAGE

    // ---- checked tail: at most QQ rows, register gather, runs once ----
    const int pt = p0 + nfull * STEP;
#pragma unroll
    for (int q = 0; q < QQ; q++) {
        if (pt + q < m) {                      // wave-uniform
            int jrow = idx[b0 + pt + q];
            const float* rp = feat + (size_t)jrow * DIM;
            float4 a0 = *(const float4*)(rp + r0), a1 = *(const float4*)(rp + r0 + 4);
            float4 bb0 = *(const float4*)(rp + c0), bb1 = *(const float4*)(rp + c0 + 4);
            float av[8] = {a0.x, a0.y, a0.z, a0.w, a1.x, a1.y, a1.z, a1.w};
            float bv[8] = {bb0.x, bb0.y, bb0.z, bb0.w, bb1.x, bb1.y, bb1.z, bb1.w};
#pragma unroll
            for (int j = 0; j < 8; j++)
#pragma unroll
                for (int kk = 0; kk < 8; kk++)
                    acc[j][kk] = fmaf(av[j], bv[kk], acc[j][kk]);
        }
    }

    // ---- phased LDS block reduction (race-free), then coalesced atomics ----
    __shared__ float tile[DIM * DIM];
    for (int w = 0; w < 4; w++) {
        if (wave == w) {
            float* t = tile + r0 * DIM + c0;
            if (w == 0) {
#pragma unroll
                for (int j = 0; j < 8; j++) {
                    *(float4*)(t + j * DIM)     = make_float4(acc[j][0], acc[j][1], acc[j][2], acc[j][3]);
                    *(float4*)(t + j * DIM + 4) = make_float4(acc[j][4], acc[j][5], acc[j][6], acc[j][7]);
                }
            } else {
#pragma unroll
                for (int j = 0; j < 8; j++) {
                    float4 u0 = *(float4*)(t + j * DIM);
                    float4 u1 = *(float4*)(t + j * DIM + 4);
                    u0.x += acc[j][0]; u0.y += acc[j][1]; u0.z += acc[j][2]; u0.w += acc[j][3];
                    u1.x += acc[j][4]; u1.y += acc[j][5]; u1.z += acc[j][6]; u1.w += acc[j][7];
                    *(float4*)(t + j * DIM)     = u0;
                    *(float4*)(t + j * DIM + 4) = u1;
                }
            }
        }
        __syncthreads();
    }
    float* g = G + c * DIM * DIM;
    for (int e = threadIdx.x; e < DIM * DIM; e += 256)
        atomicAdd(&g[e], tile[e]);
}

// ---------------- K5: top eigenvector per class (4-wave cooperative) ----
// (unchanged — validated: trace-moment shift, 7 LDS squarings to
// C=(G-sigma I)^128, column-of-max-diag start, 8 applies)
__global__ __launch_bounds__(256, 1) void k_eig(const float* __restrict__ G,
                                                float* __restrict__ V) {
    const int c    = blockIdx.x;
    const int t    = threadIdx.x;
    const int wave = t >> 6;
    const int lane = t & 63;
    __shared__ float shA[DIM * DIM];
    __shared__ float shB[DIM * DIM];
    __shared__ float shP[4 * DIM];
    __shared__ float shRed[4];
    __shared__ float shV[DIM];

    {
        const float4* g4 = (const float4*)(G + c * DIM * DIM);
        float4* a4 = (float4*)shA;
#pragma unroll
        for (int j = 0; j < 4; j++) a4[t + 256 * j] = g4[t + 256 * j];
    }
    __syncthreads();

    float ss = 0.f;
    {
        const float4* a4 = (const float4*)shA;
#pragma unroll
        for (int j = 0; j < 4; j++) {
            float4 x = a4[t + 256 * j];
            ss = fmaf(x.x, x.x, fmaf(x.y, x.y, fmaf(x.z, x.z, fmaf(x.w, x.w, ss))));
        }
    }
#pragma unroll
    for (int m = 1; m < 64; m <<= 1) ss += __shfl_xor(ss, m);
    if (lane == 0) shRed[wave] = ss;
    __syncthreads();
    if (wave == 0) {
        float s2 = shRed[0] + shRed[1] + shRed[2] + shRed[3];
        float d  = shA[lane * 65];
        float sd = d;
#pragma unroll
        for (int m = 1; m < 64; m <<= 1) sd += __shfl_xor(sd, m);
        float mu    = sd * (1.f / 64.f);
        float var   = fmaxf(s2 * (1.f / 64.f) - mu * mu, 0.f);
        float sigma = mu - 0.2f * sqrtf(var);
        shA[lane * 65] = d - sigma;
    }
    __syncthreads();

    float* cur = shA;
    float* nxt = shB;
    const int ra = wave * 16 + ((lane >> 3) << 1);
    const int c0 = (lane & 7) << 3;
    for (int sq = 0; sq < 7; sq++) {
        float acc[2][8];
#pragma unroll
        for (int j = 0; j < 8; j++) { acc[0][j] = 0.f; acc[1][j] = 0.f; }
#pragma unroll 4
        for (int k = 0; k < DIM; k++) {
            const float* rk = cur + k * DIM;
            float2 a2 = *(const float2*)(rk + ra);
            float4 b0 = *(const float4*)(rk + c0);
            float4 b1 = *(const float4*)(rk + c0 + 4);
            acc[0][0] = fmaf(a2.x, b0.x, acc[0][0]);
            acc[0][1] = fmaf(a2.x, b0.y, acc[0][1]);
            acc[0][2] = fmaf(a2.x, b0.z, acc[0][2]);
            acc[0][3] = fmaf(a2.x, b0.w, acc[0][3]);
            acc[0][4] = fmaf(a2.x, b1.x, acc[0][4]);
            acc[0][5] = fmaf(a2.x, b1.y, acc[0][5]);
            acc[0][6] = fmaf(a2.x, b1.z, acc[0][6]);
            acc[0][7] = fmaf(a2.x, b1.w, acc[0][7]);
            acc[1][0] = fmaf(a2.y, b0.x, acc[1][0]);
            acc[1][1] = fmaf(a2.y, b0.y, acc[1][1]);
            acc[1][2] = fmaf(a2.y, b0.z, acc[1][2]);
            acc[1][3] = fmaf(a2.y, b0.w, acc[1][3]);
            acc[1][4] = fmaf(a2.y, b1.x, acc[1][4]);
            acc[1][5] = fmaf(a2.y, b1.y, acc[1][5]);
            acc[1][6] = fmaf(a2.y, b1.z, acc[1][6]);
            acc[1][7] = fmaf(a2.y, b1.w, acc[1][7]);
        }
        *(float4*)(nxt + (ra + 0) * DIM + c0)     = make_float4(acc[0][0], acc[0][1], acc[0][2], acc[0][3]);
        *(float4*)(nxt + (ra + 0) * DIM + c0 + 4) = make_float4(acc[0][4], acc[0][5], acc[0][6], acc[0][7]);
        *(float4*)(nxt + (ra + 1) * DIM + c0)     = make_float4(acc[1][0], acc[1][1], acc[1][2], acc[1][3]);
        *(float4*)(nxt + (ra + 1) * DIM + c0 + 4) = make_float4(acc[1][4], acc[1][5], acc[1][6], acc[1][7]);
        __syncthreads();
        float4 xs[4];
        float mx = 0.f;
        {
            const float4* n4 = (const float4*)nxt;
#pragma unroll
            for (int j = 0; j < 4; j++) {
                float4 x = n4[t + 256 * j];
                xs[j] = x;
                mx = fmaxf(mx, fmaxf(fmaxf(fabsf(x.x), fabsf(x.y)),
                                     fmaxf(fabsf(x.z), fabsf(x.w))));
            }
        }
#pragma unroll
        for (int m = 1; m < 64; m <<= 1) mx = fmaxf(mx, __shfl_xor(mx, m));
        if (lane == 0) shRed[wave] = mx;
        __syncthreads();
        float gm = fmaxf(fmaxf(shRed[0], shRed[1]), fmaxf(shRed[2], shRed[3]));
        float inv = (gm > 0.f) ? (1.0f / gm) : 1.0f;
        {
            float4* n4 = (float4*)nxt;
#pragma unroll
            for (int j = 0; j < 4; j++) {
                float4 x = xs[j];
                n4[t + 256 * j] = make_float4(x.x * inv, x.y * inv, x.z * inv, x.w * inv);
            }
        }
        __syncthreads();
        float* tmp = cur; cur = nxt; nxt = tmp;
    }

    if (wave == 0) {
        float d = cur[lane * 65];
        float dmax = d;
#pragma unroll
        for (int m = 1; m < 64; m <<= 1) dmax = fmaxf(dmax, __shfl_xor(dmax, m));
        unsigned long long bal = __ballot(d == dmax);
        int jstar = __ffsll((long long)bal) - 1;
        shV[lane] = cur[jstar * DIM + lane];
    }
    __syncthreads();

    for (int it = 0; it < 8; it++) {
        float part = 0.f;
#pragma unroll
        for (int j = 0; j < 16; j++) {
            int k = wave * 16 + j;
            part = fmaf(cur[k * DIM + lane], shV[k], part);
        }
        shP[wave * DIM + lane] = part;
        __syncthreads();
        if (wave == 0)
            shV[lane] = shP[lane] + shP[64 + lane] + shP[128 + lane] + shP[192 + lane];
        __syncthreads();
    }

    if (wave == 0) {
        float val = shV[lane];
        float nn = val * val;
#pragma unroll
        for (int m = 1; m < 64; m <<= 1) nn += __shfl_xor(nn, m);
        float inv = (nn > 1e-30f) ? rsqrtf(nn) : 1.0f;
        float am = fabsf(val);
        float bm = am;
#pragma unroll
        for (int m = 1; m < 64; m <<= 1) bm = fmaxf(bm, __shfl_xor(bm, m));
        unsigned long long bal = __ballot(am == bm);
        int jm = __ffsll((long long)bal) - 1;
        float vm = __shfl(val, jm);
        float s = (vm < 0.f) ? -inv : inv;
        V[c * DIM + lane] = val * s;
    }
}

// ---------------- K6: given[i] = <feat_i, V[label_i]> ----------------
__global__ __launch_bounds__(256) void k_out(const float* __restrict__ feat,
                                             const int* __restrict__ label,
                                             const float* __restrict__ V,
                                             float* __restrict__ out, int n) {
    int i = blockIdx.x * blockDim.x + threadIdx.x;
    if (i >= n) return;
    const float4* rp = (const float4*)(feat + (size_t)i * DIM);
    const float4* vp = (const float4*)(V + label[i] * DIM);
    float s0 = 0, s1 = 0, s2 = 0, s3 = 0;
#pragma unroll
    for (int j = 0; j < 16; j++) {
        float4 a = rp[j], b = vp[j];
        s0 = fmaf(a.x, b.x, s0);
        s1 = fmaf(a.y, b.y, s1);
        s2 = fmaf(a.z, b.z, s2);
        s3 = fmaf(a.w, b.w, s3);
    }
    out[i] = (s0 + s1) + (s2 + s3);
}

extern "C" void kernel_launch(void* const* d_in, const int* in_sizes, int n_in,
                              void* d_out, int out_size, void* d_ws, size_t ws_size,
                              hipStream_t stream) {
    const float* feat  = (const float*)d_in[0];
    const int*   label = (const int*)d_in[1];
    const int    n     = in_sizes[1];
    float*       out   = (float*)d_out;

    // workspace layout (~2.5 MB); idx padded by 8192 ints for the
    // always-in-buffer prefetch (reads up to ~2*STEP past the last class).
    int*   wsi    = (int*)d_ws;
    int*   cnt    = wsi;                         // 16
    int*   base   = wsi + 16;                    // 16
    int*   cursor = wsi + 32;                    // 16
    int*   hpart  = wsi + 48;                    // up to 4096
    float* G      = (float*)(wsi + 4160);        // 16*4096 floats (16-B aligned)
    float* V      = G + NCLS * DIM * DIM;        // 16*64 floats
    int*   idx    = (int*)(V + NCLS * DIM);      // n + 8192 ints

    const int hblocks = (n + 2047) / 2048;       // 256 at n=524288
    k_hist<<<hblocks, 256, 0, stream>>>(label, n, hpart, G);
    k_scan<<<1, 64, 0, stream>>>(hpart, hblocks, cnt, base, cursor);
    k_scatter<<<hblocks, 256, 0, stream>>>(label, n, cursor, idx);
    k_gram<<<NCLS * GBLK, 256, 0, stream>>>(feat, idx, base, cnt, G, n);
    k_eig<<<NCLS, 256, 0, stream>>>(G, V);
    k_out<<<(n + 255) / 256, 256, 0, stream>>>(feat, label, V, out, n);
}

// Round 10
// 288.285 us; speedup vs baseline: 3.5205x; 1.0534x over previous
//
#include <hip/hip_runtime.h>
#include <math.h>

#define NCLS 16
#define DIM  64
#define GBLK 64                 // 16*64 = 1024 blocks = 256 CUs * 4 blocks/CU
#define QQ   8                  // rows per wave per iteration (2 KB stage)
#define STEP (4 * GBLK * QQ)    // 2048 rows advanced per iteration per class
#define CAP  65536              // per-class bucket capacity (counts ~32768+-175)

// ---------------- K1: single-pass bin (hist + reserve + scatter) + zero G ---
// Fixed-capacity buckets make base[c] = c*CAP a constant, so the global scan
// disappears and hist+scatter fuse into one label pass. Reservation = 16
// global atomics/block to 16 DISTINCT words (R4 lesson: never sub-bank the
// device-scope cursors); 16 LDS sub-cursors per class cut LDS contention 16x.
// cursor[] must be zeroed before launch (64-B hipMemsetAsync); its final
// value = per-class count, consumed directly by k_gram.
__global__ __launch_bounds__(256) void k_bin(const int* __restrict__ label,
                                             int n, int* __restrict__ cursor,
                                             int* __restrict__ idx,
                                             float* __restrict__ G) {
    __shared__ int h[NCLS * 16];
    __shared__ int cur[NCLS * 16];
    __shared__ int gb[NCLS];
    h[threadIdx.x] = 0;
    for (int e = blockIdx.x * 256 + threadIdx.x; e < NCLS * DIM * DIM;
         e += gridDim.x * 256)
        G[e] = 0.f;
    __syncthreads();
    const int sub = threadIdx.x & 15;
    const long i0 = (long)(blockIdx.x * 256 + threadIdx.x) * 8;
    int4 a, b;
    const bool full = (i0 + 8 <= n);
    if (full) {
        a = *(const int4*)(label + i0);
        b = *(const int4*)(label + i0 + 4);
        atomicAdd(&h[a.x * 16 + sub], 1);
        atomicAdd(&h[a.y * 16 + sub], 1);
        atomicAdd(&h[a.z * 16 + sub], 1);
        atomicAdd(&h[a.w * 16 + sub], 1);
        atomicAdd(&h[b.x * 16 + sub], 1);
        atomicAdd(&h[b.y * 16 + sub], 1);
        atomicAdd(&h[b.z * 16 + sub], 1);
        atomicAdd(&h[b.w * 16 + sub], 1);
    } else {
        for (long i = i0; i < n; i++) atomicAdd(&h[label[i] * 16 + sub], 1);
    }
    __syncthreads();
    {
        const int c = threadIdx.x >> 4, s = threadIdx.x & 15;
        int pre = 0;
        for (int j = 0; j < 16; j++) pre += (j < s) ? h[c * 16 + j] : 0;
        if (s == 15) gb[c] = atomicAdd(&cursor[c], pre + h[threadIdx.x]);
        __syncthreads();
        cur[threadIdx.x] = c * CAP + gb[c] + pre;
    }
    __syncthreads();
    if (full) {
        int p;
        p = atomicAdd(&cur[a.x * 16 + sub], 1); idx[p] = (int)i0 + 0;
        p = atomicAdd(&cur[a.y * 16 + sub], 1); idx[p] = (int)i0 + 1;
        p = atomicAdd(&cur[a.z * 16 + sub], 1); idx[p] = (int)i0 + 2;
        p = atomicAdd(&cur[a.w * 16 + sub], 1); idx[p] = (int)i0 + 3;
        p = atomicAdd(&cur[b.x * 16 + sub], 1); idx[p] = (int)i0 + 4;
        p = atomicAdd(&cur[b.y * 16 + sub], 1); idx[p] = (int)i0 + 5;
        p = atomicAdd(&cur[b.z * 16 + sub], 1); idx[p] = (int)i0 + 6;
        p = atomicAdd(&cur[b.w * 16 + sub], 1); idx[p] = (int)i0 + 7;
    } else {
        for (long i = i0; i < n; i++) {
            int p = atomicAdd(&cur[label[i] * 16 + sub], 1);
            idx[p] = (int)i;
        }
    }
}

// ---------------- K2: per-class Gram via LDS-staged gather (QQ=8) ----------
// Rows staged with global_load_lds (one instr stages 4 rows: lane->base+16B),
// two instrs per 8-row group, wave-private double-buffered, no barrier in the
// loop. Per iteration: idx(k+2) prefetch (2 b32), stage(k+1) (2 vm),
// s_waitcnt vmcnt(4) (drains stage(k)), then 512 fmas from LDS.
// base[c] = c*CAP (constant); cnt[] is k_bin's final cursor.
__global__ __launch_bounds__(256, 4) void k_gram(const float* __restrict__ feat,
                                                 const int* __restrict__ idx,
                                                 const int* __restrict__ cnt,
                                                 float* __restrict__ G,
                                                 int nrows) {
    const int c    = blockIdx.x & (NCLS - 1);
    const int blk  = blockIdx.x >> 4;          // 0..GBLK-1
    const int wave = threadIdx.x >> 6;
    const int lane = threadIdx.x & 63;
    const int gw   = blk * 4 + wave;           // 0..4*GBLK-1
    const int r0   = (lane >> 3) << 3;
    const int c0   = (lane & 7) << 3;
    const int m    = cnt[c];
    const int b0   = c * CAP;

    __shared__ float stage[4 * 2 * 512];       // 4 waves x 2 bufs x 2 KB
    float* st = stage + wave * 1024;

    float acc[8][8];
#pragma unroll
    for (int j = 0; j < 8; j++)
#pragma unroll
        for (int k = 0; k < 8; k++) acc[j][k] = 0.f;

    const int p0    = gw * QQ;
    const int nfull = (m >= p0 + QQ) ? ((m - QQ - p0) / STEP + 1) : 0;
    const int sr    = lane >> 4;               // row slot 0..3
    const int sc16  = lane & 15;               // 16-B segment within row
    const int* ippA = idx + b0 + p0 + sr;      // rows 0..3 of the group
    const int* ippB = ippA + 4;                // rows 4..7 of the group

#define STAGE(ROW, DSTF)                                                        \
    __builtin_amdgcn_global_load_lds(                                           \
        (const __attribute__((address_space(1))) void*)(feat + (size_t)(ROW) * DIM + sc16 * 4), \
        (__attribute__((address_space(3))) void*)((DSTF)), 16, 0, 0)

    int inA = 0, inB = 0;
    if (nfull > 0) {
        int a0 = ippA[0], b0r = ippB[0];       // in-range for full group 0
        STAGE(a0, st);                         // S(0) rows 0-3 -> buf 0
        STAGE(b0r, st + 256);                  // S(0) rows 4-7
        inA = ippA[STEP];                      // idx(1), may be pad/poison
        inB = ippB[STEP];
    }

    for (int k = 0; k < nfull; k++) {
        const int buf = (k & 1) << 9;          // 0 or 512 floats
        int ifA = ippA[(size_t)(k + 2) * STEP];        // prefetch, NOT used yet
        int ifB = ippB[(size_t)(k + 2) * STEP];
        int nA = ((unsigned)inA < (unsigned)nrows) ? inA : 0;  // poison-safe
        int nB = ((unsigned)inB < (unsigned)nrows) ? inB : 0;
        float* ob = st + (buf ^ 512);
        STAGE(nA, ob);                         // S(k+1) -> other buf
        STAGE(nB, ob + 256);
        asm volatile("s_waitcnt vmcnt(4)" ::: "memory");   // S(k) done
        const float* sb = st + buf;
#pragma unroll
        for (int q = 0; q < QQ; q++) {
            float4 a0 = *(const float4*)(sb + q * 64 + r0);
            float4 a1 = *(const float4*)(sb + q * 64 + r0 + 4);
            float4 bb0 = *(const float4*)(sb + q * 64 + c0);
            float4 bb1 = *(const float4*)(sb + q * 64 + c0 + 4);
            float av[8] = {a0.x, a0.y, a0.z, a0.w, a1.x, a1.y, a1.z, a1.w};
            float bv[8] = {bb0.x, bb0.y, bb0.z, bb0.w, bb1.x, bb1.y, bb1.z, bb1.w};
#pragma unroll
            for (int j = 0; j < 8; j++)
#pragma unroll
                for (int kk = 0; kk < 8; kk++)
                    acc[j][kk] = fmaf(av[j], bv[kk], acc[j][kk]);
        }
        inA = ifA; inB = ifB;
    }
    asm volatile("s_waitcnt vmcnt(0)" ::: "memory");
#undef STAGE

    // ---- checked tail: at most QQ rows, register gather, runs once ----
    const int pt = p0 + nfull * STEP;
#pragma unroll
    for (int q = 0; q < QQ; q++) {
        if (pt + q < m) {                      // wave-uniform
            int jrow = idx[b0 + pt + q];
            const float* rp = feat + (size_t)jrow * DIM;
            float4 a0 = *(const float4*)(rp + r0), a1 = *(const float4*)(rp + r0 + 4);
            float4 bb0 = *(const float4*)(rp + c0), bb1 = *(const float4*)(rp + c0 + 4);
            float av[8] = {a0.x, a0.y, a0.z, a0.w, a1.x, a1.y, a1.z, a1.w};
            float bv[8] = {bb0.x, bb0.y, bb0.z, bb0.w, bb1.x, bb1.y, bb1.z, bb1.w};
#pragma unroll
            for (int j = 0; j < 8; j++)
#pragma unroll
                for (int kk = 0; kk < 8; kk++)
                    acc[j][kk] = fmaf(av[j], bv[kk], acc[j][kk]);
        }
    }

    // ---- phased LDS block reduction (race-free), then coalesced atomics ----
    __shared__ float tile[DIM * DIM];
    for (int w = 0; w < 4; w++) {
        if (wave == w) {
            float* t = tile + r0 * DIM + c0;
            if (w == 0) {
#pragma unroll
                for (int j = 0; j < 8; j++) {
                    *(float4*)(t + j * DIM)     = make_float4(acc[j][0], acc[j][1], acc[j][2], acc[j][3]);
                    *(float4*)(t + j * DIM + 4) = make_float4(acc[j][4], acc[j][5], acc[j][6], acc[j][7]);
                }
            } else {
#pragma unroll
                for (int j = 0; j < 8; j++) {
                    float4 u0 = *(float4*)(t + j * DIM);
                    float4 u1 = *(float4*)(t + j * DIM + 4);
                    u0.x += acc[j][0]; u0.y += acc[j][1]; u0.z += acc[j][2]; u0.w += acc[j][3];
                    u1.x += acc[j][4]; u1.y += acc[j][5]; u1.z += acc[j][6]; u1.w += acc[j][7];
                    *(float4*)(t + j * DIM)     = u0;
                    *(float4*)(t + j * DIM + 4) = u1;
                }
            }
        }
        __syncthreads();
    }
    float* g = G + c * DIM * DIM;
    for (int e = threadIdx.x; e < DIM * DIM; e += 256)
        atomicAdd(&g[e], tile[e]);
}

// ---------------- K3: top eigenvector per class (4-wave cooperative) ----
// (unchanged — validated: trace-moment shift, 7 LDS squarings to
// C=(G-sigma I)^128, column-of-max-diag start, 8 applies)
__global__ __launch_bounds__(256, 1) void k_eig(const float* __restrict__ G,
                                                float* __restrict__ V) {
    const int c    = blockIdx.x;
    const int t    = threadIdx.x;
    const int wave = t >> 6;
    const int lane = t & 63;
    __shared__ float shA[DIM * DIM];
    __shared__ float shB[DIM * DIM];
    __shared__ float shP[4 * DIM];
    __shared__ float shRed[4];
    __shared__ float shV[DIM];

    {
        const float4* g4 = (const float4*)(G + c * DIM * DIM);
        float4* a4 = (float4*)shA;
#pragma unroll
        for (int j = 0; j < 4; j++) a4[t + 256 * j] = g4[t + 256 * j];
    }
    __syncthreads();

    float ss = 0.f;
    {
        const float4* a4 = (const float4*)shA;
#pragma unroll
        for (int j = 0; j < 4; j++) {
            float4 x = a4[t + 256 * j];
            ss = fmaf(x.x, x.x, fmaf(x.y, x.y, fmaf(x.z, x.z, fmaf(x.w, x.w, ss))));
        }
    }
#pragma unroll
    for (int m = 1; m < 64; m <<= 1) ss += __shfl_xor(ss, m);
    if (lane == 0) shRed[wave] = ss;
    __syncthreads();
    if (wave == 0) {
        float s2 = shRed[0] + shRed[1] + shRed[2] + shRed[3];
        float d  = shA[lane * 65];
        float sd = d;
#pragma unroll
        for (int m = 1; m < 64; m <<= 1) sd += __shfl_xor(sd, m);
        float mu    = sd * (1.f / 64.f);
        float var   = fmaxf(s2 * (1.f / 64.f) - mu * mu, 0.f);
        float sigma = mu - 0.2f * sqrtf(var);
        shA[lane * 65] = d - sigma;
    }
    __syncthreads();

    float* cur = shA;
    float* nxt = shB;
    const int ra = wave * 16 + ((lane >> 3) << 1);
    const int c0 = (lane & 7) << 3;
    for (int sq = 0; sq < 7; sq++) {
        float acc[2][8];
#pragma unroll
        for (int j = 0; j < 8; j++) { acc[0][j] = 0.f; acc[1][j] = 0.f; }
#pragma unroll 4
        for (int k = 0; k < DIM; k++) {
            const float* rk = cur + k * DIM;
            float2 a2 = *(const float2*)(rk + ra);
            float4 b0 = *(const float4*)(rk + c0);
            float4 b1 = *(const float4*)(rk + c0 + 4);
            acc[0][0] = fmaf(a2.x, b0.x, acc[0][0]);
            acc[0][1] = fmaf(a2.x, b0.y, acc[0][1]);
            acc[0][2] = fmaf(a2.x, b0.z, acc[0][2]);
            acc[0][3] = fmaf(a2.x, b0.w, acc[0][3]);
            acc[0][4] = fmaf(a2.x, b1.x, acc[0][4]);
            acc[0][5] = fmaf(a2.x, b1.y, acc[0][5]);
            acc[0][6] = fmaf(a2.x, b1.z, acc[0][6]);
            acc[0][7] = fmaf(a2.x, b1.w, acc[0][7]);
            acc[1][0] = fmaf(a2.y, b0.x, acc[1][0]);
            acc[1][1] = fmaf(a2.y, b0.y, acc[1][1]);
            acc[1][2] = fmaf(a2.y, b0.z, acc[1][2]);
            acc[1][3] = fmaf(a2.y, b0.w, acc[1][3]);
            acc[1][4] = fmaf(a2.y, b1.x, acc[1][4]);
            acc[1][5] = fmaf(a2.y, b1.y, acc[1][5]);
            acc[1][6] = fmaf(a2.y, b1.z, acc[1][6]);
            acc[1][7] = fmaf(a2.y, b1.w, acc[1][7]);
        }
        *(float4*)(nxt + (ra + 0) * DIM + c0)     = make_float4(acc[0][0], acc[0][1], acc[0][2], acc[0][3]);
        *(float4*)(nxt + (ra + 0) * DIM + c0 + 4) = make_float4(acc[0][4], acc[0][5], acc[0][6], acc[0][7]);
        *(float4*)(nxt + (ra + 1) * DIM + c0)     = make_float4(acc[1][0], acc[1][1], acc[1][2], acc[1][3]);
        *(float4*)(nxt + (ra + 1) * DIM + c0 + 4) = make_float4(acc[1][4], acc[1][5], acc[1][6], acc[1][7]);
        __syncthreads();
        float4 xs[4];
        float mx = 0.f;
        {
            const float4* n4 = (const float4*)nxt;
#pragma unroll
            for (int j = 0; j < 4; j++) {
                float4 x = n4[t + 256 * j];
                xs[j] = x;
                mx = fmaxf(mx, fmaxf(fmaxf(fabsf(x.x), fabsf(x.y)),
                                     fmaxf(fabsf(x.z), fabsf(x.w))));
            }
        }
#pragma unroll
        for (int m = 1; m < 64; m <<= 1) mx = fmaxf(mx, __shfl_xor(mx, m));
        if (lane == 0) shRed[wave] = mx;
        __syncthreads();
        float gm = fmaxf(fmaxf(shRed[0], shRed[1]), fmaxf(shRed[2], shRed[3]));
        float inv = (gm > 0.f) ? (1.0f / gm) : 1.0f;
        {
            float4* n4 = (float4*)nxt;
#pragma unroll
            for (int j = 0; j < 4; j++) {
                float4 x = xs[j];
                n4[t + 256 * j] = make_float4(x.x * inv, x.y * inv, x.z * inv, x.w * inv);
            }
        }
        __syncthreads();
        float* tmp = cur; cur = nxt; nxt = tmp;
    }

    if (wave == 0) {
        float d = cur[lane * 65];
        float dmax = d;
#pragma unroll
        for (int m = 1; m < 64; m <<= 1) dmax = fmaxf(dmax, __shfl_xor(dmax, m));
        unsigned long long bal = __ballot(d == dmax);
        int jstar = __ffsll((long long)bal) - 1;
        shV[lane] = cur[jstar * DIM + lane];
    }
    __syncthreads();

    for (int it = 0; it < 8; it++) {
        float part = 0.f;
#pragma unroll
        for (int j = 0; j < 16; j++) {
            int k = wave * 16 + j;
            part = fmaf(cur[k * DIM + lane], shV[k], part);
        }
        shP[wave * DIM + lane] = part;
        __syncthreads();
        if (wave == 0)
            shV[lane] = shP[lane] + shP[64 + lane] + shP[128 + lane] + shP[192 + lane];
        __syncthreads();
    }

    if (wave == 0) {
        float val = shV[lane];
        float nn = val * val;
#pragma unroll
        for (int m = 1; m < 64; m <<= 1) nn += __shfl_xor(nn, m);
        float inv = (nn > 1e-30f) ? rsqrtf(nn) : 1.0f;
        float am = fabsf(val);
        float bm = am;
#pragma unroll
        for (int m = 1; m < 64; m <<= 1) bm = fmaxf(bm, __shfl_xor(bm, m));
        unsigned long long bal = __ballot(am == bm);
        int jm = __ffsll((long long)bal) - 1;
        float vm = __shfl(val, jm);
        float s = (vm < 0.f) ? -inv : inv;
        V[c * DIM + lane] = val * s;
    }
}

// ---------------- K4: given[i] = <feat_i, V[label_i]> ----------------
__global__ __launch_bounds__(256) void k_out(const float* __restrict__ feat,
                                             const int* __restrict__ label,
                                             const float* __restrict__ V,
                                             float* __restrict__ out, int n) {
    int i = blockIdx.x * blockDim.x + threadIdx.x;
    if (i >= n) return;
    const float4* rp = (const float4*)(feat + (size_t)i * DIM);
    const float4* vp = (const float4*)(V + label[i] * DIM);
    float s0 = 0, s1 = 0, s2 = 0, s3 = 0;
#pragma unroll
    for (int j = 0; j < 16; j++) {
        float4 a = rp[j], b = vp[j];
        s0 = fmaf(a.x, b.x, s0);
        s1 = fmaf(a.y, b.y, s1);
        s2 = fmaf(a.z, b.z, s2);
        s3 = fmaf(a.w, b.w, s3);
    }
    out[i] = (s0 + s1) + (s2 + s3);
}

extern "C" void kernel_launch(void* const* d_in, const int* in_sizes, int n_in,
                              void* d_out, int out_size, void* d_ws, size_t ws_size,
                              hipStream_t stream) {
    const float* feat  = (const float*)d_in[0];
    const int*   label = (const int*)d_in[1];
    const int    n     = in_sizes[1];
    float*       out   = (float*)d_out;

    // workspace layout (~4.5 MB): cursor(16) | G | V | idx (16*CAP + 8K pad).
    // idx pad absorbs the always-in-buffer prefetch; poison values there are
    // clamped by the nrows check before use as row indices.
    int*   wsi    = (int*)d_ws;
    int*   cursor = wsi;                          // 16 (final = class counts)
    float* G      = (float*)(wsi + 16);           // 16*4096 floats (16-B aligned)
    float* V      = G + NCLS * DIM * DIM;         // 16*64 floats
    int*   idx    = (int*)(V + NCLS * DIM);       // 16*CAP + 8192 ints

    const int hblocks = (n + 2047) / 2048;        // 256 at n=524288
    hipMemsetAsync(cursor, 0, NCLS * sizeof(int), stream);
    k_bin<<<hblocks, 256, 0, stream>>>(label, n, cursor, idx, G);
    k_gram<<<NCLS * GBLK, 256, 0, stream>>>(feat, idx, cursor, G, n);
    k_eig<<<NCLS, 256, 0, stream>>>(G, V);
    k_out<<<(n + 255) / 256, 256, 0, stream>>>(feat, label, V, out, n);
}